// Round 14
// baseline (769.505 us; speedup 1.0000x reference)
//
#include <hip/hip_runtime.h>
#include <hip/hip_bf16.h>
#include <math.h>

#define N_NODES  10000
#define N_EDGES  160000
#define HID      128
#define N_LAYERS 6
#define N_RBF    50
#define EDGE_IN  307     // 2*HID + 1 + N_RBF
#define M_TILE   64
#define N_TILES  (N_EDGES / M_TILE)   // 2500
#define SCAN_NB  ((N_NODES + 255) / 256)   // 40

typedef short bf16x8 __attribute__((ext_vector_type(8)));
typedef float f32x4  __attribute__((ext_vector_type(4)));

__device__ __forceinline__ float silu_f(float x) {
    float e = __expf(-x);
    return x * __builtin_amdgcn_rcpf(1.0f + e);   // rcp err ~1e-6 << bf16 rounding
}
__device__ __forceinline__ short f2bf(float f) {
    union { float f; unsigned u; } v; v.f = f;
    unsigned r = v.u + 0x7FFFu + ((v.u >> 16) & 1u);   // RNE
    return (short)(r >> 16);
}
__device__ __forceinline__ float bf2f(unsigned short s) {
    union { float f; unsigned u; } v; v.u = ((unsigned)s) << 16;
    return v.f;
}
// packed RNE f32x2 -> bf16x2 (v_cvt_pk_bf16_f32 on gfx950); lo16 = a, hi16 = b
__device__ __forceinline__ unsigned pk_bf(float a, float b) {
    __hip_bfloat162 h = __float22bfloat162_rn(float2{a, b});
    unsigned u; __builtin_memcpy(&u, &h, 4); return u;
}

// ---------------- setup kernels ----------------

__global__ void init_feats_kernel(const int* __restrict__ an,
                                  const float* __restrict__ embed,
                                  short* __restrict__ featsB) {
    int idx = blockIdx.x * blockDim.x + threadIdx.x;
    if (idx < N_NODES * HID) {
        int i = idx >> 7, j = idx & 127;
        featsB[idx] = f2bf(embed[an[i] * HID + j]);
    }
}

__global__ void hist_kernel(const int* __restrict__ row, int* __restrict__ cnt) {
    int e = blockIdx.x * blockDim.x + threadIdx.x;
    if (e < N_EDGES) atomicAdd(&cnt[row[e]], 1);
}

// hierarchical scan: 40-block local exclusive scan + block totals
__global__ void scan_block_kernel(const int* __restrict__ cnt, int* __restrict__ cursor,
                                  int* __restrict__ bsum) {
    __shared__ int buf[256];
    int tid = threadIdx.x;
    int i = blockIdx.x * 256 + tid;
    int v = (i < N_NODES) ? cnt[i] : 0;
    buf[tid] = v;
    __syncthreads();
    for (int off = 1; off < 256; off <<= 1) {
        int x = (tid >= off) ? buf[tid - off] : 0;
        __syncthreads();
        buf[tid] += x;
        __syncthreads();
    }
    if (i < N_NODES) cursor[i] = buf[tid] - v;
    if (tid == 255) bsum[blockIdx.x] = buf[255];
}
__global__ void scan_tops_kernel(int* __restrict__ bsum) {
    __shared__ int buf[64];
    int tid = threadIdx.x;
    int v = (tid < SCAN_NB) ? bsum[tid] : 0;
    buf[tid] = v;
    __syncthreads();
    for (int off = 1; off < 64; off <<= 1) {
        int x = (tid >= off) ? buf[tid - off] : 0;
        __syncthreads();
        buf[tid] += x;
        __syncthreads();
    }
    if (tid < SCAN_NB) bsum[tid] = buf[tid] - v;
}
__global__ void scan_add_kernel(int* __restrict__ cursor, const int* __restrict__ bsum) {
    int i = blockIdx.x * 256 + threadIdx.x;
    if (i < N_NODES) cursor[i] += bsum[blockIdx.x];
}

__global__ void scatter_kernel(const int* __restrict__ row, int* __restrict__ cursor,
                               int* __restrict__ sorted) {
    int e = blockIdx.x * blockDim.x + threadIdx.x;
    if (e < N_EDGES) {
        int p = atomicAdd(&cursor[row[e]], 1);
        sorted[p] = e;
    }
}

// rbf table in SORTED edge order (layer-invariant; built from ORIGINAL coords):
// rbfT[p][64]: k=0 placeholder (edist patched per layer), k=1..50 rbf*cut, else 0
__global__ void rbft_kernel(const int* __restrict__ sorted,
                            const int* __restrict__ erow, const int* __restrict__ ecol,
                            const float* __restrict__ coords,
                            short* __restrict__ rbfT) {
    int p = blockIdx.x * 256 + threadIdx.x;
    if (p >= N_EDGES) return;
    int e = sorted[p];
    int r = erow[e], c = ecol[e];
    float dx = coords[3*r]   - coords[3*c];
    float dy = coords[3*r+1] - coords[3*c+1];
    float dz = coords[3*r+2] - coords[3*c+2];
    float d = sqrtf(dx*dx + dy*dy + dz*dz);
    float cut = (d < 10.0f) ? 0.5f * (__cosf(0.31415926535f * d) + 1.0f) : 0.0f;
    short* dst = &rbfT[(size_t)p * 64];
    #pragma unroll
    for (int g = 0; g < 8; ++g) {
        bf16x8 v;
        #pragma unroll
        for (int j = 0; j < 8; ++j) {
            int k = g * 8 + j;
            float val = 0.f;
            if (k >= 1 && k <= N_RBF) {
                float cen = (float)(k - 1) * (10.0f / 49.0f);
                float t = d - cen;
                val = __expf(-t * t * 5.0f) * cut;
            }
            v[j] = f2bf(val);
        }
        *(bf16x8*)&dst[g * 8] = v;
    }
}

// weight transpose+cast, per layer:
//  wtm1e [128][64]  : k=0 -> mw1 row 256 (edist); k=1..50 -> rows 257..306 (rbf); else 0
//  wtp   [256][128] : n<128 -> mw1[k][n]; n>=128 -> mw1[128+k][n-128]
//  wtm2  [128][128], wtc1 [128][128], wtf [128][256]
#define SZ_M1E 8192
#define SZ_P   32768
#define SZ_M2  16384
#define SZ_C1  16384
#define SZ_F   32768
#define WT_L   (SZ_M1E + SZ_P + SZ_M2 + SZ_C1 + SZ_F)   // 106496
__global__ void wtrans_kernel(const float* __restrict__ mw1, const float* __restrict__ mw2,
                              const float* __restrict__ cw1, const float* __restrict__ fw,
                              short* __restrict__ wtm1e, short* __restrict__ wtp,
                              short* __restrict__ wtm2, short* __restrict__ wtc1,
                              short* __restrict__ wtf) {
    int idx = blockIdx.x * blockDim.x + threadIdx.x;
    if (idx >= N_LAYERS * WT_L) return;
    int l = idx / WT_L;
    int r = idx - l * WT_L;
    const float* m1 = mw1 + (size_t)l * EDGE_IN * HID;
    if (r < SZ_M1E) {
        int n = r >> 6, k = r & 63;
        float v = 0.f;
        if (k == 0) v = m1[(size_t)256 * HID + n];
        else if (k <= 50) v = m1[(size_t)(256 + k) * HID + n];
        wtm1e[(size_t)l * SZ_M1E + r] = f2bf(v);
    } else if ((r -= SZ_M1E) < SZ_P) {
        int n = r >> 7, k = r & 127;
        float v = (n < HID) ? m1[(size_t)k * HID + n]
                            : m1[(size_t)(HID + k) * HID + (n - HID)];
        wtp[(size_t)l * SZ_P + r] = f2bf(v);
    } else if ((r -= SZ_P) < SZ_M2) {
        int n = r >> 7, k = r & 127;
        wtm2[(size_t)l * SZ_M2 + r] = f2bf(mw2[(size_t)l * HID * HID + (size_t)k * HID + n]);
    } else if ((r -= SZ_M2) < SZ_C1) {
        int n = r >> 7, k = r & 127;
        wtc1[(size_t)l * SZ_C1 + r] = f2bf(cw1[(size_t)l * HID * HID + (size_t)k * HID + n]);
    } else {
        r -= SZ_C1;
        int n = r >> 8, k = r & 255;
        wtf[(size_t)l * SZ_F + r] = f2bf(fw[(size_t)l * 2 * HID * HID + (size_t)k * HID + n]);
    }
}

// ---------------- P = feats @ mw1[0:256] (layer-0 only), 32 rows/block ----------
__global__ __launch_bounds__(256) void p_kernel(
    const short* __restrict__ featsB, const short* __restrict__ wtp,
    short* __restrict__ Pg)
{
    __shared__ short sA[32][136];
    const int tid = threadIdx.x;
    const int n0 = blockIdx.x * 32;
    const int wave = tid >> 6, lane = tid & 63, quad = lane >> 4, lm = lane & 15;

    {
        int el = tid >> 3, kq = (tid & 7) * 16;
        int node = n0 + el;
        if (node < N_NODES) {
            const bf16x8* src = (const bf16x8*)&featsB[(size_t)node * HID + kq];
            *(bf16x8*)&sA[el][kq]     = src[0];
            *(bf16x8*)&sA[el][kq + 8] = src[1];
        } else {
            *(bf16x8*)&sA[el][kq]     = (bf16x8)0;
            *(bf16x8*)&sA[el][kq + 8] = (bf16x8)0;
        }
    }
    bf16x8 bw[4][4];
    #pragma unroll
    for (int h = 0; h < 4; ++h)
        #pragma unroll
        for (int nb = 0; nb < 4; ++nb) {
            int col = wave * 64 + nb * 16 + lm;
            bw[h][nb] = *(const bf16x8*)&wtp[(size_t)col * HID + h * 32 + quad * 8];
        }
    __syncthreads();

    f32x4 acc[2][4];
    #pragma unroll
    for (int mt = 0; mt < 2; ++mt)
        #pragma unroll
        for (int nb = 0; nb < 4; ++nb) acc[mt][nb] = (f32x4)0.f;

    #pragma unroll
    for (int h = 0; h < 4; ++h) {
        bf16x8 af[2];
        af[0] = *(bf16x8*)&sA[lm][h * 32 + quad * 8];
        af[1] = *(bf16x8*)&sA[16 + lm][h * 32 + quad * 8];
        #pragma unroll
        for (int nb = 0; nb < 4; ++nb) {
            acc[0][nb] = __builtin_amdgcn_mfma_f32_16x16x32_bf16(af[0], bw[h][nb], acc[0][nb], 0, 0, 0);
            acc[1][nb] = __builtin_amdgcn_mfma_f32_16x16x32_bf16(af[1], bw[h][nb], acc[1][nb], 0, 0, 0);
        }
    }
    #pragma unroll
    for (int mt = 0; mt < 2; ++mt)
        #pragma unroll
        for (int r = 0; r < 4; ++r) {
            int node = n0 + mt * 16 + quad * 4 + r;
            if (node < N_NODES) {
                #pragma unroll
                for (int nb = 0; nb < 4; ++nb) {
                    int col = wave * 64 + nb * 16 + lm;
                    Pg[(size_t)node * 256 + col] = f2bf(acc[mt][nb][r]);
                }
            }
        }
}

// ---------------- fused per-layer edge kernel (256 thr, 32 cols/wave) ----------------
// h1 = silu(P1[row]+P2[col]+[edist|rbf]@wtm1e+b1); m = silu(h1@mw2+b2);
// c1 = silu(m@cw1+cb1); w = c1.cw2+cb2; agg += m (run-reduced); coords += w*diff.
// rbf A-fragments loaded DIRECTLY from precomputed rbfT (no LDS staging for sA);
// k=0 (edist, current coords) patched into the quad-0 fragment from sdist.

__global__ __launch_bounds__(256) void edge_kernel(
    const int* __restrict__ sorted,
    const int* __restrict__ erow, const int* __restrict__ ecol,
    const float* __restrict__ coords, float* __restrict__ coords_next,
    const short* __restrict__ Pg, const short* __restrict__ rbfT,
    const short* __restrict__ wtm1e, const float* __restrict__ mb1,
    const short* __restrict__ wtm2, const float* __restrict__ mb2,
    const short* __restrict__ wtc1, const float* __restrict__ cb1,
    const float* __restrict__ cw2, const float* __restrict__ cb2,
    float* __restrict__ agg)
{
    __shared__ short sH[M_TILE][136];   // P12 -> h1 -> m
    __shared__ int   srow[M_TILE];
    __shared__ float sdiff[M_TILE][3];
    __shared__ float sdist[M_TILE];
    __shared__ float sW[M_TILE];
    __shared__ float sWp[M_TILE][4];

    const int tid = threadIdx.x;
    const int p0 = blockIdx.x * M_TILE;
    const int wave = tid >> 6, lane = tid & 63, quad = lane >> 4, lm = lane & 15;
    const int colA = wave * 32 + lm, colB = colA + 16;
    const int el = tid >> 2, sub = tid & 3;

    // direct A-fragment loads from rbfT (independent of everything else)
    bf16x8 afr[4][2];
    #pragma unroll
    for (int mt = 0; mt < 4; ++mt)
        #pragma unroll
        for (int h = 0; h < 2; ++h)
            afr[mt][h] = *(const bf16x8*)&rbfT[(size_t)(p0 + mt * 16 + lm) * 64 + h * 32 + quad * 8];

    // per-thread edge meta (4 threads share an edge; loads L1-absorbed)
    int e = sorted[p0 + el];
    int r = erow[e], c = ecol[e];
    float dx = coords[3*r]   - coords[3*c];
    float dy = coords[3*r+1] - coords[3*c+1];
    float dz = coords[3*r+2] - coords[3*c+2];
    float ds2 = dx*dx + dy*dy + dz*dz;
    if (sub == 0) {
        srow[el] = r;
        sdiff[el][0] = dx; sdiff[el][1] = dy; sdiff[el][2] = dz;
        sdist[el] = ds2;
    }
    // per-lane bias loads (L2-hot; latency hidden under staging)
    float b1A = mb1[colA], b1B = mb1[colB];
    float b2A = mb2[colA], b2B = mb2[colB];
    float c1A = cb1[colA], c1B = cb1[colB];
    float vA  = cw2[colA], vB  = cw2[colB];
    const float cb2v = cb2[0];

    // ---- stage P12 = P1[row] + P2[col] into sH (4 thr/row, 32 cols each) ----
    {
        int kq = sub * 32;
        const short* p1 = &Pg[(size_t)r * 256 + kq];
        const short* p2 = &Pg[(size_t)c * 256 + 128 + kq];
        #pragma unroll
        for (int g = 0; g < 4; ++g) {
            bf16x8 a = *(const bf16x8*)&p1[g * 8];
            bf16x8 b = *(const bf16x8*)&p2[g * 8];
            bf16x8 o;
            #pragma unroll
            for (int j = 0; j < 8; j += 2) {
                float s0 = bf2f((unsigned short)a[j])     + bf2f((unsigned short)b[j]);
                float s1 = bf2f((unsigned short)a[j + 1]) + bf2f((unsigned short)b[j + 1]);
                unsigned u = pk_bf(s0, s1);
                o[j] = (short)(u & 0xFFFF); o[j + 1] = (short)(u >> 16);
            }
            *(bf16x8*)&sH[el][kq + g * 8] = o;
        }
    }
    // B prefetch: phase-1 + phase-2 frags ride the same pre-barrier window
    bf16x8 bw1[2][2];
    #pragma unroll
    for (int h = 0; h < 2; ++h) {
        bw1[h][0] = *(const bf16x8*)&wtm1e[(size_t)colA * 64 + h * 32 + quad * 8];
        bw1[h][1] = *(const bf16x8*)&wtm1e[(size_t)colB * 64 + h * 32 + quad * 8];
    }
    bf16x8 bw2[4][2];
    #pragma unroll
    for (int ks = 0; ks < 4; ++ks) {
        bw2[ks][0] = *(const bf16x8*)&wtm2[(size_t)colA * HID + ks * 32 + quad * 8];
        bw2[ks][1] = *(const bf16x8*)&wtm2[(size_t)colB * HID + ks * 32 + quad * 8];
    }
    __syncthreads();

    // patch k=0 (edist from CURRENT coords) into quad-0/h-0 fragments
    if (quad == 0) {
        #pragma unroll
        for (int mt = 0; mt < 4; ++mt)
            afr[mt][0][0] = f2bf(sdist[mt * 16 + lm]);
    }

    f32x4 acc[4][2];
    #pragma unroll
    for (int mt = 0; mt < 4; ++mt) { acc[mt][0] = (f32x4)0.f; acc[mt][1] = (f32x4)0.f; }

    // ---- phase 1: rbf GEMM, K=64 (16 MFMA), A from registers ----
    #pragma unroll
    for (int h = 0; h < 2; ++h)
        #pragma unroll
        for (int nb = 0; nb < 2; ++nb)
            #pragma unroll
            for (int mt = 0; mt < 4; ++mt)
                acc[mt][nb] = __builtin_amdgcn_mfma_f32_16x16x32_bf16(
                    afr[mt][h], bw1[h][nb], acc[mt][nb], 0, 0, 0);
    // epilogue 1: h1 = silu(acc + P12 + b1), in-place in sH (element-exclusive per lane)
    #pragma unroll
    for (int mt = 0; mt < 4; ++mt) {
        #pragma unroll
        for (int r2 = 0; r2 < 4; ++r2) {
            int row = mt * 16 + quad * 4 + r2;
            float pA = bf2f((unsigned short)sH[row][colA]);
            float pB = bf2f((unsigned short)sH[row][colB]);
            float hA = silu_f(acc[mt][0][r2] + pA + b1A);
            float hB = silu_f(acc[mt][1][r2] + pB + b1B);
            unsigned u = pk_bf(hA, hB);
            sH[row][colA] = (short)(u & 0xFFFF);
            sH[row][colB] = (short)(u >> 16);
        }
        acc[mt][0] = (f32x4)0.f; acc[mt][1] = (f32x4)0.f;
    }
    __syncthreads();

    // ---- phase 2: m = silu(h1 @ mw2 + b2), K=128 (32 MFMA) ----
    #pragma unroll
    for (int ks = 0; ks < 4; ++ks) {
        bf16x8 af[4];
        #pragma unroll
        for (int mt = 0; mt < 4; ++mt)
            af[mt] = *(bf16x8*)&sH[mt * 16 + lm][ks * 32 + quad * 8];
        #pragma unroll
        for (int nb = 0; nb < 2; ++nb)
            #pragma unroll
            for (int mt = 0; mt < 4; ++mt)
                acc[mt][nb] = __builtin_amdgcn_mfma_f32_16x16x32_bf16(
                    af[mt], bw2[ks][nb], acc[mt][nb], 0, 0, 0);
    }
    // prefetch phase-3 B; latency hidden by epilogue-2
    bf16x8 bw3[4][2];
    #pragma unroll
    for (int ks = 0; ks < 4; ++ks) {
        bw3[ks][0] = *(const bf16x8*)&wtc1[(size_t)colA * HID + ks * 32 + quad * 8];
        bw3[ks][1] = *(const bf16x8*)&wtc1[(size_t)colB * HID + ks * 32 + quad * 8];
    }
    __syncthreads();   // phase-2 reads done before overwrite
    // epilogue 2: silu+bias; run-reduce agg atomics; write m -> sH
    #pragma unroll
    for (int nb = 0; nb < 2; ++nb) {
        int col = wave * 32 + nb * 16 + lm;
        float b = nb ? b2B : b2A;
        #pragma unroll
        for (int mt = 0; mt < 4; ++mt) {
            float g = 0.f;
            #pragma unroll
            for (int r2 = 0; r2 < 4; ++r2) {
                int row = mt * 16 + quad * 4 + r2;
                float mv = silu_f(acc[mt][nb][r2] + b);
                sH[row][col] = f2bf(mv);
                g += mv;
                if (r2 == 3 || srow[row + 1] != srow[row]) {
                    atomicAdd(&agg[(size_t)srow[row] * HID + col], g);
                    g = 0.f;
                }
            }
            acc[mt][nb] = (f32x4)0.f;
        }
    }
    __syncthreads();

    // ---- phase 3: c1 = silu(m @ cw1 + cb1), K=128 (32 MFMA) ----
    #pragma unroll
    for (int ks = 0; ks < 4; ++ks) {
        bf16x8 af[4];
        #pragma unroll
        for (int mt = 0; mt < 4; ++mt)
            af[mt] = *(bf16x8*)&sH[mt * 16 + lm][ks * 32 + quad * 8];
        #pragma unroll
        for (int nb = 0; nb < 2; ++nb)
            #pragma unroll
            for (int mt = 0; mt < 4; ++mt)
                acc[mt][nb] = __builtin_amdgcn_mfma_f32_16x16x32_bf16(
                    af[mt], bw3[ks][nb], acc[mt][nb], 0, 0, 0);
    }
    // epilogue 3: w-dot from accumulators via quad shfl-reduce
    {
        float wp[4][4];
        #pragma unroll
        for (int mt = 0; mt < 4; ++mt)
            #pragma unroll
            for (int r2 = 0; r2 < 4; ++r2) wp[mt][r2] = 0.f;
        #pragma unroll
        for (int nb = 0; nb < 2; ++nb) {
            float b = nb ? c1B : c1A;
            float vv = nb ? vB : vA;
            #pragma unroll
            for (int mt = 0; mt < 4; ++mt)
                #pragma unroll
                for (int r2 = 0; r2 < 4; ++r2)
                    wp[mt][r2] += silu_f(acc[mt][nb][r2] + b) * vv;
        }
        #pragma unroll
        for (int mt = 0; mt < 4; ++mt)
            #pragma unroll
            for (int r2 = 0; r2 < 4; ++r2) {
                float v = wp[mt][r2];
                v += __shfl_xor(v, 1); v += __shfl_xor(v, 2);
                v += __shfl_xor(v, 4); v += __shfl_xor(v, 8);
                if (lm == 0) sWp[mt * 16 + quad * 4 + r2][wave] = v;
            }
    }
    __syncthreads();
    if (tid < M_TILE)
        sW[tid] = cb2v + sWp[tid][0] + sWp[tid][1] + sWp[tid][2] + sWp[tid][3];
    __syncthreads();
    if (tid < M_TILE) {
        bool leader = (tid == 0) || (srow[tid] != srow[tid - 1]);
        if (leader) {
            int rr = srow[tid];
            float ax = 0.f, ay = 0.f, az = 0.f;
            for (int k = tid; k < M_TILE && srow[k] == rr; ++k) {
                ax += sW[k] * sdiff[k][0];
                ay += sW[k] * sdiff[k][1];
                az += sW[k] * sdiff[k][2];
            }
            atomicAdd(&coords_next[3*rr+0], ax);
            atomicAdd(&coords_next[3*rr+1], ay);
            atomicAdd(&coords_next[3*rr+2], az);
        }
    }
}

// ---------------- node update (fused, R12 structure): feats' = silu([feats|agg]@fw+fb);
// zeroes agg after reading; copies coords csrc->cdst; computes P'=feats'@wtp_next.
__global__ __launch_bounds__(256) void node_kernel(
    const short* __restrict__ featsB, float* __restrict__ agg,
    const short* __restrict__ wtf, const float* __restrict__ fb,
    short* __restrict__ outB,
    const short* __restrict__ wtp_next, short* __restrict__ Pg,
    const float* __restrict__ csrc, float* __restrict__ cdst)
{
    __shared__ short sA[32][72];
    __shared__ short sO[32][136];

    const int tid = threadIdx.x;
    const int n0 = blockIdx.x * 32;
    const int wave = tid >> 6, lane = tid & 63, quad = lane >> 4, lm = lane & 15;

    {   // coords copy for next layer (spread over grid)
        int idx = blockIdx.x * 256 + tid;
        if (idx < 3 * N_NODES) cdst[idx] = csrc[idx];
    }
    float fbA = fb[wave * 32 + lm], fbB = fb[wave * 32 + 16 + lm];

    f32x4 acc[2][2];
    acc[0][0] = (f32x4)0.f; acc[0][1] = (f32x4)0.f;
    acc[1][0] = (f32x4)0.f; acc[1][1] = (f32x4)0.f;

    for (int c = 0; c < 4; ++c) {   // K = 256, 4 chunks of 64
        int k0 = c * 64;
        bf16x8 bw[2][2];
        #pragma unroll
        for (int h = 0; h < 2; ++h) {
            int col0 = wave * 32 + lm;
            bw[h][0] = *(const bf16x8*)&wtf[(size_t)col0 * 256 + k0 + h * 32 + quad * 8];
            bw[h][1] = *(const bf16x8*)&wtf[(size_t)(col0 + 16) * 256 + k0 + h * 32 + quad * 8];
        }
        {
            int el = tid >> 3, kq = (tid & 7) * 8;
            int node = n0 + el;
            if (node < N_NODES) {
                if (c < 2) {
                    *(bf16x8*)&sA[el][kq] =
                        *(const bf16x8*)&featsB[(size_t)node * HID + k0 + kq];
                } else {
                    float* ap = &agg[(size_t)node * HID + (k0 - 128) + kq];
                    bf16x8 v;
                    #pragma unroll
                    for (int j = 0; j < 8; j += 2) {
                        unsigned u = pk_bf(ap[j], ap[j + 1]);
                        v[j] = (short)(u & 0xFFFF); v[j + 1] = (short)(u >> 16);
                    }
                    *(bf16x8*)&sA[el][kq] = v;
                    // zero agg for the next layer (each element touched exactly once)
                    *(float4*)&ap[0] = make_float4(0.f, 0.f, 0.f, 0.f);
                    *(float4*)&ap[4] = make_float4(0.f, 0.f, 0.f, 0.f);
                }
            } else {
                *(bf16x8*)&sA[el][kq] = (bf16x8)0;
            }
        }
        __syncthreads();
        #pragma unroll
        for (int h = 0; h < 2; ++h) {
            bf16x8 af[2];
            af[0] = *(bf16x8*)&sA[lm][h * 32 + quad * 8];
            af[1] = *(bf16x8*)&sA[16 + lm][h * 32 + quad * 8];
            #pragma unroll
            for (int nb = 0; nb < 2; ++nb) {
                acc[0][nb] = __builtin_amdgcn_mfma_f32_16x16x32_bf16(af[0], bw[h][nb], acc[0][nb], 0, 0, 0);
                acc[1][nb] = __builtin_amdgcn_mfma_f32_16x16x32_bf16(af[1], bw[h][nb], acc[1][nb], 0, 0, 0);
            }
        }
        __syncthreads();
    }
    // prefetch P-GEMM B frags (latency hidden by epilogue)
    bf16x8 bwp[4][4];
    if (wtp_next) {
        #pragma unroll
        for (int ks = 0; ks < 4; ++ks)
            #pragma unroll
            for (int nb = 0; nb < 4; ++nb) {
                int col = wave * 64 + nb * 16 + lm;
                bwp[ks][nb] = *(const bf16x8*)&wtp_next[(size_t)col * HID + ks * 32 + quad * 8];
            }
    }
    // epilogue: silu+bias -> sO
    #pragma unroll
    for (int mt = 0; mt < 2; ++mt) {
        #pragma unroll
        for (int r = 0; r < 4; ++r) {
            int row = mt * 16 + quad * 4 + r;
            float hA = silu_f(acc[mt][0][r] + fbA);
            float hB = silu_f(acc[mt][1][r] + fbB);
            unsigned u = pk_bf(hA, hB);
            sO[row][wave * 32 + lm]      = (short)(u & 0xFFFF);
            sO[row][wave * 32 + 16 + lm] = (short)(u >> 16);
        }
    }
    __syncthreads();
    {   // coalesced feats' write
        int row = tid >> 3, ch = (tid & 7) * 8;
        int node = n0 + row;
        if (node < N_NODES) {
            *(bf16x8*)&outB[(size_t)node * HID + ch]      = *(bf16x8*)&sO[row][ch];
            *(bf16x8*)&outB[(size_t)node * HID + 64 + ch] = *(bf16x8*)&sO[row][64 + ch];
        }
    }
    // ---- P' = feats' @ wtp_next (K=128, 256 cols), reads sO ----
    if (wtp_next) {
        f32x4 ap2[2][4];
        #pragma unroll
        for (int mt = 0; mt < 2; ++mt)
            #pragma unroll
            for (int nb = 0; nb < 4; ++nb) ap2[mt][nb] = (f32x4)0.f;
        #pragma unroll
        for (int ks = 0; ks < 4; ++ks) {
            bf16x8 af[2];
            af[0] = *(bf16x8*)&sO[lm][ks * 32 + quad * 8];
            af[1] = *(bf16x8*)&sO[16 + lm][ks * 32 + quad * 8];
            #pragma unroll
            for (int nb = 0; nb < 4; ++nb) {
                ap2[0][nb] = __builtin_amdgcn_mfma_f32_16x16x32_bf16(af[0], bwp[ks][nb], ap2[0][nb], 0, 0, 0);
                ap2[1][nb] = __builtin_amdgcn_mfma_f32_16x16x32_bf16(af[1], bwp[ks][nb], ap2[1][nb], 0, 0, 0);
            }
        }
        #pragma unroll
        for (int mt = 0; mt < 2; ++mt)
            #pragma unroll
            for (int r = 0; r < 4; ++r) {
                int node = n0 + mt * 16 + quad * 4 + r;
                if (node < N_NODES) {
                    #pragma unroll
                    for (int nb = 0; nb < 4; ++nb) {
                        int col = wave * 64 + nb * 16 + lm;
                        Pg[(size_t)node * 256 + col] = f2bf(ap2[mt][nb][r]);
                    }
                }
            }
    }
}

// ---------------- energy head + global sum ----------------
#define FMA8(r, aq) \
    acc[r][0] += (aq)*b0.x; acc[r][1] += (aq)*b0.y; acc[r][2] += (aq)*b0.z; acc[r][3] += (aq)*b0.w; \
    acc[r][4] += (aq)*b1.x; acc[r][5] += (aq)*b1.y; acc[r][6] += (aq)*b1.z; acc[r][7] += (aq)*b1.w;

__global__ __launch_bounds__(256) void energy_kernel(
    const short* __restrict__ featsB,
    const float* __restrict__ ew1, const float* __restrict__ eb1,
    const float* __restrict__ ew2, const float* __restrict__ eb2,
    float* __restrict__ out)
{
    __shared__ float sA[64][20];
    __shared__ float sB[16][HID];
    __shared__ float sV[HID];
    __shared__ float red[256];
    int tid = threadIdx.x;
    int n0 = blockIdx.x * 64;
    const int tr = tid >> 4, tc = tid & 15;
    const int r0 = tr * 4, c0 = tc * 4, c1 = c0 + 64;
    const int el = tid >> 2, kq = (tid & 3) * 4;

    if (tid < HID) sV[tid] = ew2[tid];

    float acc[4][8];
    #pragma unroll
    for (int i = 0; i < 4; i++)
        #pragma unroll
        for (int j = 0; j < 8; j++) acc[i][j] = 0.f;

    for (int kt = 0; kt < 8; ++kt) {   // K = 128
        int k0 = kt * 16;
        {
            int k = k0 + kq;
            int node = n0 + el;
            float4 v = make_float4(0,0,0,0);
            if (node < N_NODES) {
                const unsigned short* p = (const unsigned short*)&featsB[(size_t)node * HID + k];
                v.x = bf2f(p[0]); v.y = bf2f(p[1]); v.z = bf2f(p[2]); v.w = bf2f(p[3]);
            }
            *(float4*)&sA[el][kq] = v;
        }
        {
            int bk = tid >> 4, bj = (tid & 15) * 8;
            int k = k0 + bk;
            *(float4*)&sB[bk][bj]     = *(const float4*)&ew1[(size_t)k * HID + bj];
            *(float4*)&sB[bk][bj + 4] = *(const float4*)&ew1[(size_t)k * HID + bj + 4];
        }
        __syncthreads();
        #pragma unroll
        for (int kk4 = 0; kk4 < 4; ++kk4) {
            float4 a0 = *(const float4*)&sA[r0 + 0][kk4 * 4];
            float4 a1 = *(const float4*)&sA[r0 + 1][kk4 * 4];
            float4 a2 = *(const float4*)&sA[r0 + 2][kk4 * 4];
            float4 a3 = *(const float4*)&sA[r0 + 3][kk4 * 4];
            #pragma unroll
            for (int q = 0; q < 4; ++q) {
                int kk = kk4 * 4 + q;
                float4 b0 = *(const float4*)&sB[kk][c0];
                float4 b1 = *(const float4*)&sB[kk][c1];
                float q0 = ((const float*)&a0)[q], q1 = ((const float*)&a1)[q];
                float q2 = ((const float*)&a2)[q], q3 = ((const float*)&a3)[q];
                FMA8(0, q0) FMA8(1, q1) FMA8(2, q2) FMA8(3, q3)
            }
        }
        __syncthreads();
    }
    float part = 0.f;
    #pragma unroll
    for (int i = 0; i < 4; i++) {
        int node = n0 + r0 + i;
        if (node < N_NODES) {
            #pragma unroll
            for (int j = 0; j < 4; j++) {
                part += silu_f(acc[i][j]     + eb1[c0+j]) * sV[c0+j];
                part += silu_f(acc[i][4 + j] + eb1[c1+j]) * sV[c1+j];
            }
        }
    }
    red[tid] = part;
    __syncthreads();
    for (int s = 128; s > 0; s >>= 1) {
        if (tid < s) red[tid] += red[tid + s];
        __syncthreads();
    }
    if (tid == 0) {
        float v = red[0];
        if (blockIdx.x == 0) v += eb2[0] * (float)N_NODES;
        atomicAdd(out, v);
    }
}

// ---------------- launcher ----------------

extern "C" void kernel_launch(void* const* d_in, const int* in_sizes, int n_in,
                              void* d_out, int out_size, void* d_ws, size_t ws_size,
                              hipStream_t stream)
{
    const int*   an     = (const int*)  d_in[0];
    const float* coords = (const float*)d_in[1];
    const int*   ei     = (const int*)  d_in[2];
    const float* embed  = (const float*)d_in[3];
    const float* mw1 = (const float*)d_in[4];
    const float* mb1 = (const float*)d_in[5];
    const float* mw2 = (const float*)d_in[6];
    const float* mb2 = (const float*)d_in[7];
    const float* cw1 = (const float*)d_in[8];
    const float* cb1 = (const float*)d_in[9];
    const float* cw2 = (const float*)d_in[10];
    const float* cb2 = (const float*)d_in[11];
    const float* fw  = (const float*)d_in[12];
    const float* fb  = (const float*)d_in[13];
    const float* ew1 = (const float*)d_in[14];
    const float* eb1 = (const float*)d_in[15];
    const float* ew2 = (const float*)d_in[16];
    const float* eb2 = (const float*)d_in[17];
    float* out = (float*)d_out;

    char* w = (char*)d_ws;
    size_t off = 0;
    auto alloc = [&](size_t bytes) -> char* {
        char* p = w + off;
        off = (off + bytes + 511) & ~(size_t)511;
        return p;
    };
    short* featsB0 = (short*)alloc((size_t)N_NODES * HID * 2);
    short* featsB1 = (short*)alloc((size_t)N_NODES * HID * 2);
    short* Pg      = (short*)alloc((size_t)N_NODES * 256 * 2);
    float* agg     = (float*)alloc((size_t)N_NODES * HID * 4);
    float* cA      = (float*)alloc((size_t)N_NODES * 3 * 4);
    float* cB      = (float*)alloc((size_t)N_NODES * 3 * 4);
    short* rbfT    = (short*)alloc((size_t)N_EDGES * 64 * 2);   // 20.5 MB
    int*   sorted  = (int*)  alloc((size_t)N_EDGES * 4);
    int*   cnt     = (int*)  alloc((size_t)N_NODES * 4);
    int*   cursor  = (int*)  alloc((size_t)N_NODES * 4);
    int*   bsum    = (int*)  alloc((size_t)64 * 4);
    short* wtm1e   = (short*)alloc((size_t)N_LAYERS * SZ_M1E * 2);
    short* wtp     = (short*)alloc((size_t)N_LAYERS * SZ_P * 2);
    short* wtm2    = (short*)alloc((size_t)N_LAYERS * SZ_M2 * 2);
    short* wtc1    = (short*)alloc((size_t)N_LAYERS * SZ_C1 * 2);
    short* wtf     = (short*)alloc((size_t)N_LAYERS * SZ_F * 2);

    const int* erow = ei;
    const int* ecol = ei + N_EDGES;

    hipMemsetAsync(cnt, 0, (size_t)N_NODES * 4, stream);
    hipMemsetAsync(agg, 0, (size_t)N_NODES * HID * 4, stream);
    init_feats_kernel<<<(N_NODES * HID + 255) / 256, 256, 0, stream>>>(an, embed, featsB0);
    wtrans_kernel<<<(N_LAYERS * WT_L + 255) / 256, 256, 0, stream>>>(
        mw1, mw2, cw1, fw, wtm1e, wtp, wtm2, wtc1, wtf);
    hipMemcpyAsync(cA, coords, (size_t)N_NODES * 3 * 4, hipMemcpyDeviceToDevice, stream);
    hipMemcpyAsync(cB, coords, (size_t)N_NODES * 3 * 4, hipMemcpyDeviceToDevice, stream);
    hist_kernel<<<(N_EDGES + 255) / 256, 256, 0, stream>>>(erow, cnt);
    scan_block_kernel<<<SCAN_NB, 256, 0, stream>>>(cnt, cursor, bsum);
    scan_tops_kernel<<<1, 64, 0, stream>>>(bsum);
    scan_add_kernel<<<SCAN_NB, 256, 0, stream>>>(cursor, bsum);
    scatter_kernel<<<(N_EDGES + 255) / 256, 256, 0, stream>>>(erow, cursor, sorted);
    rbft_kernel<<<(N_EDGES + 255) / 256, 256, 0, stream>>>(sorted, erow, ecol, cA, rbfT);
    p_kernel<<<(N_NODES + 31) / 32, 256, 0, stream>>>(featsB0, wtp, Pg);

    short* fc = featsB0; short* fn = featsB1;
    float* cc = cA;      float* cn = cB;
    for (int l = 0; l < N_LAYERS; ++l) {
        edge_kernel<<<N_TILES, 256, 0, stream>>>(
            sorted, erow, ecol, cc, cn, Pg, rbfT,
            wtm1e + (size_t)l * SZ_M1E, mb1 + (size_t)l * HID,
            wtm2  + (size_t)l * SZ_M2,  mb2 + (size_t)l * HID,
            wtc1  + (size_t)l * SZ_C1,  cb1 + (size_t)l * HID,
            cw2 + (size_t)l * HID,      cb2 + l, agg);
        // node: feats update + agg zeroing + coords copy (cn -> cc) + P' for next layer
        node_kernel<<<(N_NODES + 31) / 32, 256, 0, stream>>>(
            fc, agg, wtf + (size_t)l * SZ_F, fb + (size_t)l * HID, fn,
            (l + 1 < N_LAYERS) ? (wtp + (size_t)(l + 1) * SZ_P) : (const short*)nullptr,
            Pg, cn, cc);
        { short* t = fc; fc = fn; fn = t; }
        { float* t = cc; cc = cn; cn = t; }
    }
    hipMemsetAsync(out, 0, 4, stream);
    energy_kernel<<<(N_NODES + 63) / 64, 256, 0, stream>>>(fc, ew1, eb1, ew2, eb2, out);
}

// Round 15
// 691.361 us; speedup vs baseline: 1.1130x; 1.1130x over previous
//
#include <hip/hip_runtime.h>
#include <hip/hip_bf16.h>
#include <math.h>

#define N_NODES  10000
#define N_EDGES  160000
#define HID      128
#define N_LAYERS 6
#define N_RBF    50
#define EDGE_IN  307     // 2*HID + 1 + N_RBF
#define M_TILE   64
#define N_TILES  (N_EDGES / M_TILE)   // 2500
#define SCAN_NB  ((N_NODES + 255) / 256)   // 40

typedef short bf16x8 __attribute__((ext_vector_type(8)));
typedef float f32x4  __attribute__((ext_vector_type(4)));

__device__ __forceinline__ float silu_f(float x) {
    float e = __expf(-x);
    return x * __builtin_amdgcn_rcpf(1.0f + e);   // rcp err ~1e-6 << bf16 rounding
}
__device__ __forceinline__ short f2bf(float f) {
    union { float f; unsigned u; } v; v.f = f;
    unsigned r = v.u + 0x7FFFu + ((v.u >> 16) & 1u);   // RNE
    return (short)(r >> 16);
}
__device__ __forceinline__ float bf2f(unsigned short s) {
    union { float f; unsigned u; } v; v.u = ((unsigned)s) << 16;
    return v.f;
}
// packed RNE f32x2 -> bf16x2 (v_cvt_pk_bf16_f32 on gfx950); lo16 = a, hi16 = b
__device__ __forceinline__ unsigned pk_bf(float a, float b) {
    __hip_bfloat162 h = __float22bfloat162_rn(float2{a, b});
    unsigned u; __builtin_memcpy(&u, &h, 4); return u;
}

// ---------------- setup kernels ----------------

__global__ void init_feats_kernel(const int* __restrict__ an,
                                  const float* __restrict__ embed,
                                  short* __restrict__ featsB) {
    int idx = blockIdx.x * blockDim.x + threadIdx.x;
    if (idx < N_NODES * HID) {
        int i = idx >> 7, j = idx & 127;
        featsB[idx] = f2bf(embed[an[i] * HID + j]);
    }
}

__global__ void hist_kernel(const int* __restrict__ row, int* __restrict__ cnt) {
    int e = blockIdx.x * blockDim.x + threadIdx.x;
    if (e < N_EDGES) atomicAdd(&cnt[row[e]], 1);
}

// hierarchical scan: 40-block local exclusive scan + block totals
__global__ void scan_block_kernel(const int* __restrict__ cnt, int* __restrict__ cursor,
                                  int* __restrict__ bsum) {
    __shared__ int buf[256];
    int tid = threadIdx.x;
    int i = blockIdx.x * 256 + tid;
    int v = (i < N_NODES) ? cnt[i] : 0;
    buf[tid] = v;
    __syncthreads();
    for (int off = 1; off < 256; off <<= 1) {
        int x = (tid >= off) ? buf[tid - off] : 0;
        __syncthreads();
        buf[tid] += x;
        __syncthreads();
    }
    if (i < N_NODES) cursor[i] = buf[tid] - v;
    if (tid == 255) bsum[blockIdx.x] = buf[255];
}
__global__ void scan_tops_kernel(int* __restrict__ bsum) {
    __shared__ int buf[64];
    int tid = threadIdx.x;
    int v = (tid < SCAN_NB) ? bsum[tid] : 0;
    buf[tid] = v;
    __syncthreads();
    for (int off = 1; off < 64; off <<= 1) {
        int x = (tid >= off) ? buf[tid - off] : 0;
        __syncthreads();
        buf[tid] += x;
        __syncthreads();
    }
    if (tid < SCAN_NB) bsum[tid] = buf[tid] - v;
}
__global__ void scan_add_kernel(int* __restrict__ cursor, const int* __restrict__ bsum) {
    int i = blockIdx.x * 256 + threadIdx.x;
    if (i < N_NODES) cursor[i] += bsum[blockIdx.x];
}

__global__ void scatter_kernel(const int* __restrict__ row, int* __restrict__ cursor,
                               int* __restrict__ sorted) {
    int e = blockIdx.x * blockDim.x + threadIdx.x;
    if (e < N_EDGES) {
        int p = atomicAdd(&cursor[row[e]], 1);
        sorted[p] = e;
    }
}

__global__ void edgegeom_kernel(const int* __restrict__ sorted,
                                const int* __restrict__ erow, const int* __restrict__ ecol,
                                const float* __restrict__ coords,
                                float* __restrict__ d0, float* __restrict__ cut0) {
    int p = blockIdx.x * 256 + threadIdx.x;
    if (p < N_EDGES) {
        int e = sorted[p];
        int r = erow[e], c = ecol[e];
        float dx = coords[3*r]   - coords[3*c];
        float dy = coords[3*r+1] - coords[3*c+1];
        float dz = coords[3*r+2] - coords[3*c+2];
        float d = sqrtf(dx*dx + dy*dy + dz*dz);
        d0[p] = d;
        cut0[p] = (d < 10.0f) ? 0.5f * (__cosf(0.31415926535f * d) + 1.0f) : 0.0f;
    }
}

// weight transpose+cast, per layer:
//  wtm1e [128][64]  : k=0 -> mw1 row 256 (edist); k=1..50 -> rows 257..306 (rbf); else 0
//  wtp   [256][128] : n<128 -> mw1[k][n]; n>=128 -> mw1[128+k][n-128]
//  wtm2  [128][128], wtc1 [128][128], wtf [128][256]
#define SZ_M1E 8192
#define SZ_P   32768
#define SZ_M2  16384
#define SZ_C1  16384
#define SZ_F   32768
#define WT_L   (SZ_M1E + SZ_P + SZ_M2 + SZ_C1 + SZ_F)   // 106496
__global__ void wtrans_kernel(const float* __restrict__ mw1, const float* __restrict__ mw2,
                              const float* __restrict__ cw1, const float* __restrict__ fw,
                              short* __restrict__ wtm1e, short* __restrict__ wtp,
                              short* __restrict__ wtm2, short* __restrict__ wtc1,
                              short* __restrict__ wtf) {
    int idx = blockIdx.x * blockDim.x + threadIdx.x;
    if (idx >= N_LAYERS * WT_L) return;
    int l = idx / WT_L;
    int r = idx - l * WT_L;
    const float* m1 = mw1 + (size_t)l * EDGE_IN * HID;
    if (r < SZ_M1E) {
        int n = r >> 6, k = r & 63;
        float v = 0.f;
        if (k == 0) v = m1[(size_t)256 * HID + n];
        else if (k <= 50) v = m1[(size_t)(256 + k) * HID + n];
        wtm1e[(size_t)l * SZ_M1E + r] = f2bf(v);
    } else if ((r -= SZ_M1E) < SZ_P) {
        int n = r >> 7, k = r & 127;
        float v = (n < HID) ? m1[(size_t)k * HID + n]
                            : m1[(size_t)(HID + k) * HID + (n - HID)];
        wtp[(size_t)l * SZ_P + r] = f2bf(v);
    } else if ((r -= SZ_P) < SZ_M2) {
        int n = r >> 7, k = r & 127;
        wtm2[(size_t)l * SZ_M2 + r] = f2bf(mw2[(size_t)l * HID * HID + (size_t)k * HID + n]);
    } else if ((r -= SZ_M2) < SZ_C1) {
        int n = r >> 7, k = r & 127;
        wtc1[(size_t)l * SZ_C1 + r] = f2bf(cw1[(size_t)l * HID * HID + (size_t)k * HID + n]);
    } else {
        r -= SZ_C1;
        int n = r >> 8, k = r & 255;
        wtf[(size_t)l * SZ_F + r] = f2bf(fw[(size_t)l * 2 * HID * HID + (size_t)k * HID + n]);
    }
}

// ---------------- P = feats @ mw1[0:256] (layer-0 only), 32 rows/block ----------
__global__ __launch_bounds__(256) void p_kernel(
    const short* __restrict__ featsB, const short* __restrict__ wtp,
    short* __restrict__ Pg)
{
    __shared__ short sA[32][136];
    const int tid = threadIdx.x;
    const int n0 = blockIdx.x * 32;
    const int wave = tid >> 6, lane = tid & 63, quad = lane >> 4, lm = lane & 15;

    {
        int el = tid >> 3, kq = (tid & 7) * 16;
        int node = n0 + el;
        if (node < N_NODES) {
            const bf16x8* src = (const bf16x8*)&featsB[(size_t)node * HID + kq];
            *(bf16x8*)&sA[el][kq]     = src[0];
            *(bf16x8*)&sA[el][kq + 8] = src[1];
        } else {
            *(bf16x8*)&sA[el][kq]     = (bf16x8)0;
            *(bf16x8*)&sA[el][kq + 8] = (bf16x8)0;
        }
    }
    bf16x8 bw[4][4];
    #pragma unroll
    for (int h = 0; h < 4; ++h)
        #pragma unroll
        for (int nb = 0; nb < 4; ++nb) {
            int col = wave * 64 + nb * 16 + lm;
            bw[h][nb] = *(const bf16x8*)&wtp[(size_t)col * HID + h * 32 + quad * 8];
        }
    __syncthreads();

    f32x4 acc[2][4];
    #pragma unroll
    for (int mt = 0; mt < 2; ++mt)
        #pragma unroll
        for (int nb = 0; nb < 4; ++nb) acc[mt][nb] = (f32x4)0.f;

    #pragma unroll
    for (int h = 0; h < 4; ++h) {
        bf16x8 af[2];
        af[0] = *(bf16x8*)&sA[lm][h * 32 + quad * 8];
        af[1] = *(bf16x8*)&sA[16 + lm][h * 32 + quad * 8];
        #pragma unroll
        for (int nb = 0; nb < 4; ++nb) {
            acc[0][nb] = __builtin_amdgcn_mfma_f32_16x16x32_bf16(af[0], bw[h][nb], acc[0][nb], 0, 0, 0);
            acc[1][nb] = __builtin_amdgcn_mfma_f32_16x16x32_bf16(af[1], bw[h][nb], acc[1][nb], 0, 0, 0);
        }
    }
    #pragma unroll
    for (int mt = 0; mt < 2; ++mt)
        #pragma unroll
        for (int r = 0; r < 4; ++r) {
            int node = n0 + mt * 16 + quad * 4 + r;
            if (node < N_NODES) {
                #pragma unroll
                for (int nb = 0; nb < 4; ++nb) {
                    int col = wave * 64 + nb * 16 + lm;
                    Pg[(size_t)node * 256 + col] = f2bf(acc[mt][nb][r]);
                }
            }
        }
}

// ---------------- fused per-layer edge kernel (R12 structure, unchanged) ----------------
__global__ __launch_bounds__(256) void edge_kernel(
    const int* __restrict__ sorted,
    const int* __restrict__ erow, const int* __restrict__ ecol,
    const float* __restrict__ coords, float* __restrict__ coords_next,
    const short* __restrict__ Pg,
    const float* __restrict__ d0g, const float* __restrict__ cut0g,
    const short* __restrict__ wtm1e, const float* __restrict__ mb1,
    const short* __restrict__ wtm2, const float* __restrict__ mb2,
    const short* __restrict__ wtc1, const float* __restrict__ cb1,
    const float* __restrict__ cw2, const float* __restrict__ cb2,
    float* __restrict__ agg)
{
    __shared__ short sH[M_TILE][136];   // P12 -> h1 -> m
    __shared__ short sA[M_TILE][72];    // rbf K-chunk
    __shared__ int   srow[M_TILE];
    __shared__ float sdiff[M_TILE][3];
    __shared__ float sW[M_TILE];
    __shared__ float sWp[M_TILE][4];

    const int tid = threadIdx.x;
    const int p0 = blockIdx.x * M_TILE;
    const int wave = tid >> 6, lane = tid & 63, quad = lane >> 4, lm = lane & 15;
    const int colA = wave * 32 + lm, colB = colA + 16;
    const int el = tid >> 2, sub = tid & 3;

    int e = sorted[p0 + el];
    int r = erow[e], c = ecol[e];
    float dx = coords[3*r]   - coords[3*c];
    float dy = coords[3*r+1] - coords[3*c+1];
    float dz = coords[3*r+2] - coords[3*c+2];
    float ds2 = dx*dx + dy*dy + dz*dz;
    if (sub == 0) {
        srow[el] = r;
        sdiff[el][0] = dx; sdiff[el][1] = dy; sdiff[el][2] = dz;
    }
    float b1A = mb1[colA], b1B = mb1[colB];
    float b2A = mb2[colA], b2B = mb2[colB];
    float c1A = cb1[colA], c1B = cb1[colB];
    float vA  = cw2[colA], vB  = cw2[colB];
    const float cb2v = cb2[0];

    // ---- stage P12 = P1[row] + P2[col] into sH (4 thr/row, 32 cols each) ----
    {
        int kq = sub * 32;
        const short* p1 = &Pg[(size_t)r * 256 + kq];
        const short* p2 = &Pg[(size_t)c * 256 + 128 + kq];
        #pragma unroll
        for (int g = 0; g < 4; ++g) {
            bf16x8 a = *(const bf16x8*)&p1[g * 8];
            bf16x8 b = *(const bf16x8*)&p2[g * 8];
            bf16x8 o;
            #pragma unroll
            for (int j = 0; j < 8; j += 2) {
                float s0 = bf2f((unsigned short)a[j])     + bf2f((unsigned short)b[j]);
                float s1 = bf2f((unsigned short)a[j + 1]) + bf2f((unsigned short)b[j + 1]);
                unsigned u = pk_bf(s0, s1);
                o[j] = (short)(u & 0xFFFF); o[j + 1] = (short)(u >> 16);
            }
            *(bf16x8*)&sH[el][kq + g * 8] = o;
        }
    }
    // ---- stage rbf chunk into sA (4 thr/row, 16 k each): k=0 edist, 1..50 rbf ----
    {
        float dv = d0g[p0 + el], ct = cut0g[p0 + el];
        int kq = sub * 16;
        #pragma unroll
        for (int g = 0; g < 2; ++g) {
            bf16x8 v;
            #pragma unroll
            for (int j = 0; j < 8; ++j) {
                int k = kq + g * 8 + j;
                float val = 0.f;
                if (k == 0) val = ds2;
                else if (k <= N_RBF) {
                    float cen = (float)(k - 1) * (10.0f / 49.0f);
                    float t = dv - cen;
                    val = __expf(-t * t * 5.0f) * ct;
                }
                v[j] = f2bf(val);
            }
            *(bf16x8*)&sA[el][kq + g * 8] = v;
        }
    }
    // B prefetch: phase-1 + phase-2 frags ride the same pre-barrier window
    bf16x8 bw1[2][2];
    #pragma unroll
    for (int h = 0; h < 2; ++h) {
        bw1[h][0] = *(const bf16x8*)&wtm1e[(size_t)colA * 64 + h * 32 + quad * 8];
        bw1[h][1] = *(const bf16x8*)&wtm1e[(size_t)colB * 64 + h * 32 + quad * 8];
    }
    bf16x8 bw2[4][2];
    #pragma unroll
    for (int ks = 0; ks < 4; ++ks) {
        bw2[ks][0] = *(const bf16x8*)&wtm2[(size_t)colA * HID + ks * 32 + quad * 8];
        bw2[ks][1] = *(const bf16x8*)&wtm2[(size_t)colB * HID + ks * 32 + quad * 8];
    }
    __syncthreads();

    f32x4 acc[4][2];
    #pragma unroll
    for (int mt = 0; mt < 4; ++mt) { acc[mt][0] = (f32x4)0.f; acc[mt][1] = (f32x4)0.f; }

    // ---- phase 1: rbf GEMM, K=64 (16 MFMA) ----
    #pragma unroll
    for (int h = 0; h < 2; ++h) {
        bf16x8 af[4];
        #pragma unroll
        for (int mt = 0; mt < 4; ++mt)
            af[mt] = *(bf16x8*)&sA[mt * 16 + lm][h * 32 + quad * 8];
        #pragma unroll
        for (int nb = 0; nb < 2; ++nb)
            #pragma unroll
            for (int mt = 0; mt < 4; ++mt)
                acc[mt][nb] = __builtin_amdgcn_mfma_f32_16x16x32_bf16(
                    af[mt], bw1[h][nb], acc[mt][nb], 0, 0, 0);
    }
    // epilogue 1: h1 = silu(acc + P12 + b1), in-place in sH
    #pragma unroll
    for (int mt = 0; mt < 4; ++mt) {
        #pragma unroll
        for (int r2 = 0; r2 < 4; ++r2) {
            int row = mt * 16 + quad * 4 + r2;
            float pA = bf2f((unsigned short)sH[row][colA]);
            float pB = bf2f((unsigned short)sH[row][colB]);
            float hA = silu_f(acc[mt][0][r2] + pA + b1A);
            float hB = silu_f(acc[mt][1][r2] + pB + b1B);
            unsigned u = pk_bf(hA, hB);
            sH[row][colA] = (short)(u & 0xFFFF);
            sH[row][colB] = (short)(u >> 16);
        }
        acc[mt][0] = (f32x4)0.f; acc[mt][1] = (f32x4)0.f;
    }
    __syncthreads();

    // ---- phase 2: m = silu(h1 @ mw2 + b2), K=128 (32 MFMA) ----
    #pragma unroll
    for (int ks = 0; ks < 4; ++ks) {
        bf16x8 af[4];
        #pragma unroll
        for (int mt = 0; mt < 4; ++mt)
            af[mt] = *(bf16x8*)&sH[mt * 16 + lm][ks * 32 + quad * 8];
        #pragma unroll
        for (int nb = 0; nb < 2; ++nb)
            #pragma unroll
            for (int mt = 0; mt < 4; ++mt)
                acc[mt][nb] = __builtin_amdgcn_mfma_f32_16x16x32_bf16(
                    af[mt], bw2[ks][nb], acc[mt][nb], 0, 0, 0);
    }
    bf16x8 bw3[4][2];
    #pragma unroll
    for (int ks = 0; ks < 4; ++ks) {
        bw3[ks][0] = *(const bf16x8*)&wtc1[(size_t)colA * HID + ks * 32 + quad * 8];
        bw3[ks][1] = *(const bf16x8*)&wtc1[(size_t)colB * HID + ks * 32 + quad * 8];
    }
    __syncthreads();
    // epilogue 2: silu+bias; run-reduce agg atomics; write m -> sH
    #pragma unroll
    for (int nb = 0; nb < 2; ++nb) {
        int col = wave * 32 + nb * 16 + lm;
        float b = nb ? b2B : b2A;
        #pragma unroll
        for (int mt = 0; mt < 4; ++mt) {
            float g = 0.f;
            #pragma unroll
            for (int r2 = 0; r2 < 4; ++r2) {
                int row = mt * 16 + quad * 4 + r2;
                float mv = silu_f(acc[mt][nb][r2] + b);
                sH[row][col] = f2bf(mv);
                g += mv;
                if (r2 == 3 || srow[row + 1] != srow[row]) {
                    atomicAdd(&agg[(size_t)srow[row] * HID + col], g);
                    g = 0.f;
                }
            }
            acc[mt][nb] = (f32x4)0.f;
        }
    }
    __syncthreads();

    // ---- phase 3: c1 = silu(m @ cw1 + cb1), K=128 (32 MFMA) ----
    #pragma unroll
    for (int ks = 0; ks < 4; ++ks) {
        bf16x8 af[4];
        #pragma unroll
        for (int mt = 0; mt < 4; ++mt)
            af[mt] = *(bf16x8*)&sH[mt * 16 + lm][ks * 32 + quad * 8];
        #pragma unroll
        for (int nb = 0; nb < 2; ++nb)
            #pragma unroll
            for (int mt = 0; mt < 4; ++mt)
                acc[mt][nb] = __builtin_amdgcn_mfma_f32_16x16x32_bf16(
                    af[mt], bw3[ks][nb], acc[mt][nb], 0, 0, 0);
    }
    // epilogue 3: w-dot from accumulators via quad shfl-reduce
    {
        float wp[4][4];
        #pragma unroll
        for (int mt = 0; mt < 4; ++mt)
            #pragma unroll
            for (int r2 = 0; r2 < 4; ++r2) wp[mt][r2] = 0.f;
        #pragma unroll
        for (int nb = 0; nb < 2; ++nb) {
            float b = nb ? c1B : c1A;
            float vv = nb ? vB : vA;
            #pragma unroll
            for (int mt = 0; mt < 4; ++mt)
                #pragma unroll
                for (int r2 = 0; r2 < 4; ++r2)
                    wp[mt][r2] += silu_f(acc[mt][nb][r2] + b) * vv;
        }
        #pragma unroll
        for (int mt = 0; mt < 4; ++mt)
            #pragma unroll
            for (int r2 = 0; r2 < 4; ++r2) {
                float v = wp[mt][r2];
                v += __shfl_xor(v, 1); v += __shfl_xor(v, 2);
                v += __shfl_xor(v, 4); v += __shfl_xor(v, 8);
                if (lm == 0) sWp[mt * 16 + quad * 4 + r2][wave] = v;
            }
    }
    __syncthreads();
    if (tid < M_TILE)
        sW[tid] = cb2v + sWp[tid][0] + sWp[tid][1] + sWp[tid][2] + sWp[tid][3];
    __syncthreads();
    if (tid < M_TILE) {
        bool leader = (tid == 0) || (srow[tid] != srow[tid - 1]);
        if (leader) {
            int rr = srow[tid];
            float ax = 0.f, ay = 0.f, az = 0.f;
            for (int k = tid; k < M_TILE && srow[k] == rr; ++k) {
                ax += sW[k] * sdiff[k][0];
                ay += sW[k] * sdiff[k][1];
                az += sW[k] * sdiff[k][2];
            }
            atomicAdd(&coords_next[3*rr+0], ax);
            atomicAdd(&coords_next[3*rr+1], ay);
            atomicAdd(&coords_next[3*rr+2], az);
        }
    }
}

// ---------------- node update (fused, 16 rows/block = 625 blocks) ----------------
// feats' = silu([feats|agg]@fw+fb); zeroes agg; copies coords; P'=feats'@wtp_next.
__global__ __launch_bounds__(256) void node_kernel(
    const short* __restrict__ featsB, float* __restrict__ agg,
    const short* __restrict__ wtf, const float* __restrict__ fb,
    short* __restrict__ outB,
    const short* __restrict__ wtp_next, short* __restrict__ Pg,
    const float* __restrict__ csrc, float* __restrict__ cdst)
{
    __shared__ short sA[16][136];
    __shared__ short sO[16][136];

    const int tid = threadIdx.x;
    const int n0 = blockIdx.x * 16;   // N_NODES % 16 == 0 -> no bounds checks
    const int wave = tid >> 6, lane = tid & 63, quad = lane >> 4, lm = lane & 15;

    {   // coords copy for next layer (spread over grid)
        int idx = blockIdx.x * 256 + tid;
        if (idx < 3 * N_NODES) cdst[idx] = csrc[idx];
    }
    float fbA = fb[wave * 32 + lm], fbB = fb[wave * 32 + 16 + lm];

    f32x4 acc[2];
    acc[0] = (f32x4)0.f; acc[1] = (f32x4)0.f;

    for (int ch = 0; ch < 2; ++ch) {   // K = 256, 2 chunks of 128
        int k0 = ch * 128;
        bf16x8 bw[4][2];
        #pragma unroll
        for (int ks = 0; ks < 4; ++ks) {
            int col0 = wave * 32 + lm;
            bw[ks][0] = *(const bf16x8*)&wtf[(size_t)col0 * 256 + k0 + ks * 32 + quad * 8];
            bw[ks][1] = *(const bf16x8*)&wtf[(size_t)(col0 + 16) * 256 + k0 + ks * 32 + quad * 8];
        }
        {   // stage 16 rows x 128 k: 16 thr/row, 8 shorts each
            int el = tid >> 4, kq = (tid & 15) * 8;
            int node = n0 + el;
            if (ch == 0) {
                *(bf16x8*)&sA[el][kq] =
                    *(const bf16x8*)&featsB[(size_t)node * HID + kq];
            } else {
                float* ap = &agg[(size_t)node * HID + kq];
                bf16x8 v;
                #pragma unroll
                for (int j = 0; j < 8; j += 2) {
                    unsigned u = pk_bf(ap[j], ap[j + 1]);
                    v[j] = (short)(u & 0xFFFF); v[j + 1] = (short)(u >> 16);
                }
                *(bf16x8*)&sA[el][kq] = v;
                // zero agg for the next layer (each element touched exactly once)
                *(float4*)&ap[0] = make_float4(0.f, 0.f, 0.f, 0.f);
                *(float4*)&ap[4] = make_float4(0.f, 0.f, 0.f, 0.f);
            }
        }
        __syncthreads();
        #pragma unroll
        for (int ks = 0; ks < 4; ++ks) {
            bf16x8 af = *(bf16x8*)&sA[lm][ks * 32 + quad * 8];
            acc[0] = __builtin_amdgcn_mfma_f32_16x16x32_bf16(af, bw[ks][0], acc[0], 0, 0, 0);
            acc[1] = __builtin_amdgcn_mfma_f32_16x16x32_bf16(af, bw[ks][1], acc[1], 0, 0, 0);
        }
        __syncthreads();
    }
    // prefetch P-GEMM B frags (latency hidden by epilogue)
    bf16x8 bwp[4][4];
    if (wtp_next) {
        #pragma unroll
        for (int ks = 0; ks < 4; ++ks)
            #pragma unroll
            for (int nb = 0; nb < 4; ++nb) {
                int col = wave * 64 + nb * 16 + lm;
                bwp[ks][nb] = *(const bf16x8*)&wtp_next[(size_t)col * HID + ks * 32 + quad * 8];
            }
    }
    // epilogue: silu+bias -> sO
    #pragma unroll
    for (int r = 0; r < 4; ++r) {
        int row = quad * 4 + r;
        float hA = silu_f(acc[0][r] + fbA);
        float hB = silu_f(acc[1][r] + fbB);
        unsigned u = pk_bf(hA, hB);
        sO[row][wave * 32 + lm]      = (short)(u & 0xFFFF);
        sO[row][wave * 32 + 16 + lm] = (short)(u >> 16);
    }
    __syncthreads();
    {   // coalesced feats' write: 16 thr/row, 8 shorts each
        int row = tid >> 4, ch2 = (tid & 15) * 8;
        int node = n0 + row;
        *(bf16x8*)&outB[(size_t)node * HID + ch2] = *(bf16x8*)&sO[row][ch2];
    }
    // ---- P' = feats' @ wtp_next (K=128, 256 cols), reads sO ----
    if (wtp_next) {
        f32x4 ap2[4];
        #pragma unroll
        for (int nb = 0; nb < 4; ++nb) ap2[nb] = (f32x4)0.f;
        #pragma unroll
        for (int ks = 0; ks < 4; ++ks) {
            bf16x8 af = *(bf16x8*)&sO[lm][ks * 32 + quad * 8];
            #pragma unroll
            for (int nb = 0; nb < 4; ++nb)
                ap2[nb] = __builtin_amdgcn_mfma_f32_16x16x32_bf16(af, bwp[ks][nb], ap2[nb], 0, 0, 0);
        }
        #pragma unroll
        for (int r = 0; r < 4; ++r) {
            int node = n0 + quad * 4 + r;
            #pragma unroll
            for (int nb = 0; nb < 4; ++nb) {
                int col = wave * 64 + nb * 16 + lm;
                Pg[(size_t)node * 256 + col] = f2bf(ap2[nb][r]);
            }
        }
    }
}

// ---------------- energy head + global sum ----------------
#define FMA8(r, aq) \
    acc[r][0] += (aq)*b0.x; acc[r][1] += (aq)*b0.y; acc[r][2] += (aq)*b0.z; acc[r][3] += (aq)*b0.w; \
    acc[r][4] += (aq)*b1.x; acc[r][5] += (aq)*b1.y; acc[r][6] += (aq)*b1.z; acc[r][7] += (aq)*b1.w;

__global__ __launch_bounds__(256) void energy_kernel(
    const short* __restrict__ featsB,
    const float* __restrict__ ew1, const float* __restrict__ eb1,
    const float* __restrict__ ew2, const float* __restrict__ eb2,
    float* __restrict__ out)
{
    __shared__ float sA[64][20];
    __shared__ float sB[16][HID];
    __shared__ float sV[HID];
    __shared__ float red[256];
    int tid = threadIdx.x;
    int n0 = blockIdx.x * 64;
    const int tr = tid >> 4, tc = tid & 15;
    const int r0 = tr * 4, c0 = tc * 4, c1 = c0 + 64;
    const int el = tid >> 2, kq = (tid & 3) * 4;

    if (tid < HID) sV[tid] = ew2[tid];

    float acc[4][8];
    #pragma unroll
    for (int i = 0; i < 4; i++)
        #pragma unroll
        for (int j = 0; j < 8; j++) acc[i][j] = 0.f;

    for (int kt = 0; kt < 8; ++kt) {   // K = 128
        int k0 = kt * 16;
        {
            int k = k0 + kq;
            int node = n0 + el;
            float4 v = make_float4(0,0,0,0);
            if (node < N_NODES) {
                const unsigned short* p = (const unsigned short*)&featsB[(size_t)node * HID + k];
                v.x = bf2f(p[0]); v.y = bf2f(p[1]); v.z = bf2f(p[2]); v.w = bf2f(p[3]);
            }
            *(float4*)&sA[el][kq] = v;
        }
        {
            int bk = tid >> 4, bj = (tid & 15) * 8;
            int k = k0 + bk;
            *(float4*)&sB[bk][bj]     = *(const float4*)&ew1[(size_t)k * HID + bj];
            *(float4*)&sB[bk][bj + 4] = *(const float4*)&ew1[(size_t)k * HID + bj + 4];
        }
        __syncthreads();
        #pragma unroll
        for (int kk4 = 0; kk4 < 4; ++kk4) {
            float4 a0 = *(const float4*)&sA[r0 + 0][kk4 * 4];
            float4 a1 = *(const float4*)&sA[r0 + 1][kk4 * 4];
            float4 a2 = *(const float4*)&sA[r0 + 2][kk4 * 4];
            float4 a3 = *(const float4*)&sA[r0 + 3][kk4 * 4];
            #pragma unroll
            for (int q = 0; q < 4; ++q) {
                int kk = kk4 * 4 + q;
                float4 b0 = *(const float4*)&sB[kk][c0];
                float4 b1 = *(const float4*)&sB[kk][c1];
                float q0 = ((const float*)&a0)[q], q1 = ((const float*)&a1)[q];
                float q2 = ((const float*)&a2)[q], q3 = ((const float*)&a3)[q];
                FMA8(0, q0) FMA8(1, q1) FMA8(2, q2) FMA8(3, q3)
            }
        }
        __syncthreads();
    }
    float part = 0.f;
    #pragma unroll
    for (int i = 0; i < 4; i++) {
        int node = n0 + r0 + i;
        if (node < N_NODES) {
            #pragma unroll
            for (int j = 0; j < 4; j++) {
                part += silu_f(acc[i][j]     + eb1[c0+j]) * sV[c0+j];
                part += silu_f(acc[i][4 + j] + eb1[c1+j]) * sV[c1+j];
            }
        }
    }
    red[tid] = part;
    __syncthreads();
    for (int s = 128; s > 0; s >>= 1) {
        if (tid < s) red[tid] += red[tid + s];
        __syncthreads();
    }
    if (tid == 0) {
        float v = red[0];
        if (blockIdx.x == 0) v += eb2[0] * (float)N_NODES;
        atomicAdd(out, v);
    }
}

// ---------------- launcher ----------------

extern "C" void kernel_launch(void* const* d_in, const int* in_sizes, int n_in,
                              void* d_out, int out_size, void* d_ws, size_t ws_size,
                              hipStream_t stream)
{
    const int*   an     = (const int*)  d_in[0];
    const float* coords = (const float*)d_in[1];
    const int*   ei     = (const int*)  d_in[2];
    const float* embed  = (const float*)d_in[3];
    const float* mw1 = (const float*)d_in[4];
    const float* mb1 = (const float*)d_in[5];
    const float* mw2 = (const float*)d_in[6];
    const float* mb2 = (const float*)d_in[7];
    const float* cw1 = (const float*)d_in[8];
    const float* cb1 = (const float*)d_in[9];
    const float* cw2 = (const float*)d_in[10];
    const float* cb2 = (const float*)d_in[11];
    const float* fw  = (const float*)d_in[12];
    const float* fb  = (const float*)d_in[13];
    const float* ew1 = (const float*)d_in[14];
    const float* eb1 = (const float*)d_in[15];
    const float* ew2 = (const float*)d_in[16];
    const float* eb2 = (const float*)d_in[17];
    float* out = (float*)d_out;

    char* w = (char*)d_ws;
    size_t off = 0;
    auto alloc = [&](size_t bytes) -> char* {
        char* p = w + off;
        off = (off + bytes + 511) & ~(size_t)511;
        return p;
    };
    short* featsB0 = (short*)alloc((size_t)N_NODES * HID * 2);
    short* featsB1 = (short*)alloc((size_t)N_NODES * HID * 2);
    short* Pg      = (short*)alloc((size_t)N_NODES * 256 * 2);
    float* agg     = (float*)alloc((size_t)N_NODES * HID * 4);
    float* cA      = (float*)alloc((size_t)N_NODES * 3 * 4);
    float* cB      = (float*)alloc((size_t)N_NODES * 3 * 4);
    float* d0      = (float*)alloc((size_t)N_EDGES * 4);
    float* cut0    = (float*)alloc((size_t)N_EDGES * 4);
    int*   sorted  = (int*)  alloc((size_t)N_EDGES * 4);
    int*   cnt     = (int*)  alloc((size_t)N_NODES * 4);
    int*   cursor  = (int*)  alloc((size_t)N_NODES * 4);
    int*   bsum    = (int*)  alloc((size_t)64 * 4);
    short* wtm1e   = (short*)alloc((size_t)N_LAYERS * SZ_M1E * 2);
    short* wtp     = (short*)alloc((size_t)N_LAYERS * SZ_P * 2);
    short* wtm2    = (short*)alloc((size_t)N_LAYERS * SZ_M2 * 2);
    short* wtc1    = (short*)alloc((size_t)N_LAYERS * SZ_C1 * 2);
    short* wtf     = (short*)alloc((size_t)N_LAYERS * SZ_F * 2);

    const int* erow = ei;
    const int* ecol = ei + N_EDGES;

    hipMemsetAsync(cnt, 0, (size_t)N_NODES * 4, stream);
    hipMemsetAsync(agg, 0, (size_t)N_NODES * HID * 4, stream);
    init_feats_kernel<<<(N_NODES * HID + 255) / 256, 256, 0, stream>>>(an, embed, featsB0);
    wtrans_kernel<<<(N_LAYERS * WT_L + 255) / 256, 256, 0, stream>>>(
        mw1, mw2, cw1, fw, wtm1e, wtp, wtm2, wtc1, wtf);
    hipMemcpyAsync(cA, coords, (size_t)N_NODES * 3 * 4, hipMemcpyDeviceToDevice, stream);
    hipMemcpyAsync(cB, coords, (size_t)N_NODES * 3 * 4, hipMemcpyDeviceToDevice, stream);
    hist_kernel<<<(N_EDGES + 255) / 256, 256, 0, stream>>>(erow, cnt);
    scan_block_kernel<<<SCAN_NB, 256, 0, stream>>>(cnt, cursor, bsum);
    scan_tops_kernel<<<1, 64, 0, stream>>>(bsum);
    scan_add_kernel<<<SCAN_NB, 256, 0, stream>>>(cursor, bsum);
    scatter_kernel<<<(N_EDGES + 255) / 256, 256, 0, stream>>>(erow, cursor, sorted);
    edgegeom_kernel<<<N_EDGES / 256, 256, 0, stream>>>(sorted, erow, ecol, cA, d0, cut0);
    p_kernel<<<(N_NODES + 31) / 32, 256, 0, stream>>>(featsB0, wtp, Pg);

    short* fc = featsB0; short* fn = featsB1;
    float* cc = cA;      float* cn = cB;
    for (int l = 0; l < N_LAYERS; ++l) {
        edge_kernel<<<N_TILES, 256, 0, stream>>>(
            sorted, erow, ecol, cc, cn, Pg, d0, cut0,
            wtm1e + (size_t)l * SZ_M1E, mb1 + (size_t)l * HID,
            wtm2  + (size_t)l * SZ_M2,  mb2 + (size_t)l * HID,
            wtc1  + (size_t)l * SZ_C1,  cb1 + (size_t)l * HID,
            cw2 + (size_t)l * HID,      cb2 + l, agg);
        node_kernel<<<N_NODES / 16, 256, 0, stream>>>(
            fc, agg, wtf + (size_t)l * SZ_F, fb + (size_t)l * HID, fn,
            (l + 1 < N_LAYERS) ? (wtp + (size_t)(l + 1) * SZ_P) : (const short*)nullptr,
            Pg, cn, cc);
        { short* t = fc; fc = fn; fn = t; }
        { float* t = cc; cc = cn; cn = t; }
    }
    hipMemsetAsync(out, 0, 4, stream);
    energy_kernel<<<(N_NODES + 63) / 64, 256, 0, stream>>>(fc, ew1, eb1, ew2, eb2, out);
}

// Round 16
// 673.568 us; speedup vs baseline: 1.1424x; 1.0264x over previous
//
#include <hip/hip_runtime.h>
#include <hip/hip_bf16.h>
#include <math.h>

#define N_NODES  10000
#define N_EDGES  160000
#define HID      128
#define N_LAYERS 6
#define N_RBF    50
#define EDGE_IN  307     // 2*HID + 1 + N_RBF
#define M_TILE   64
#define N_TILES  (N_EDGES / M_TILE)   // 2500
#define SCAN_NB  ((N_NODES + 255) / 256)   // 40

typedef short bf16x8 __attribute__((ext_vector_type(8)));
typedef float f32x4  __attribute__((ext_vector_type(4)));

__device__ __forceinline__ float silu_f(float x) {
    float e = __expf(-x);
    return x * __builtin_amdgcn_rcpf(1.0f + e);   // rcp err ~1e-6 << bf16 rounding
}
__device__ __forceinline__ short f2bf(float f) {
    union { float f; unsigned u; } v; v.f = f;
    unsigned r = v.u + 0x7FFFu + ((v.u >> 16) & 1u);   // RNE
    return (short)(r >> 16);
}
__device__ __forceinline__ float bf2f(unsigned short s) {
    union { float f; unsigned u; } v; v.u = ((unsigned)s) << 16;
    return v.f;
}
// packed RNE f32x2 -> bf16x2 (v_cvt_pk_bf16_f32 on gfx950); lo16 = a, hi16 = b
__device__ __forceinline__ unsigned pk_bf(float a, float b) {
    __hip_bfloat162 h = __float22bfloat162_rn(float2{a, b});
    unsigned u; __builtin_memcpy(&u, &h, 4); return u;
}

// ---------------- setup kernels ----------------

__global__ void init_feats_kernel(const int* __restrict__ an,
                                  const float* __restrict__ embed,
                                  short* __restrict__ featsB) {
    int idx = blockIdx.x * blockDim.x + threadIdx.x;
    if (idx < N_NODES * HID) {
        int i = idx >> 7, j = idx & 127;
        featsB[idx] = f2bf(embed[an[i] * HID + j]);
    }
}

__global__ void hist_kernel(const int* __restrict__ row, int* __restrict__ cnt) {
    int e = blockIdx.x * blockDim.x + threadIdx.x;
    if (e < N_EDGES) atomicAdd(&cnt[row[e]], 1);
}

// hierarchical scan: 40-block local exclusive scan + block totals
__global__ void scan_block_kernel(const int* __restrict__ cnt, int* __restrict__ cursor,
                                  int* __restrict__ bsum) {
    __shared__ int buf[256];
    int tid = threadIdx.x;
    int i = blockIdx.x * 256 + tid;
    int v = (i < N_NODES) ? cnt[i] : 0;
    buf[tid] = v;
    __syncthreads();
    for (int off = 1; off < 256; off <<= 1) {
        int x = (tid >= off) ? buf[tid - off] : 0;
        __syncthreads();
        buf[tid] += x;
        __syncthreads();
    }
    if (i < N_NODES) cursor[i] = buf[tid] - v;
    if (tid == 255) bsum[blockIdx.x] = buf[255];
}
__global__ void scan_tops_kernel(int* __restrict__ bsum) {
    __shared__ int buf[64];
    int tid = threadIdx.x;
    int v = (tid < SCAN_NB) ? bsum[tid] : 0;
    buf[tid] = v;
    __syncthreads();
    for (int off = 1; off < 64; off <<= 1) {
        int x = (tid >= off) ? buf[tid - off] : 0;
        __syncthreads();
        buf[tid] += x;
        __syncthreads();
    }
    if (tid < SCAN_NB) bsum[tid] = buf[tid] - v;
}

// scatter with bsum folded in: global position = local scan + bsum[node block]
__global__ void scatter_kernel(const int* __restrict__ row, int* __restrict__ cursor,
                               const int* __restrict__ bsum, int* __restrict__ sorted) {
    int e = blockIdx.x * blockDim.x + threadIdx.x;
    if (e < N_EDGES) {
        int rr = row[e];
        int p = atomicAdd(&cursor[rr], 1) + bsum[rr >> 8];
        sorted[p] = e;
    }
}

__global__ void edgegeom_kernel(const int* __restrict__ sorted,
                                const int* __restrict__ erow, const int* __restrict__ ecol,
                                const float* __restrict__ coords,
                                float* __restrict__ d0, float* __restrict__ cut0) {
    int p = blockIdx.x * 256 + threadIdx.x;
    if (p < N_EDGES) {
        int e = sorted[p];
        int r = erow[e], c = ecol[e];
        float dx = coords[3*r]   - coords[3*c];
        float dy = coords[3*r+1] - coords[3*c+1];
        float dz = coords[3*r+2] - coords[3*c+2];
        float d = sqrtf(dx*dx + dy*dy + dz*dz);
        d0[p] = d;
        cut0[p] = (d < 10.0f) ? 0.5f * (__cosf(0.31415926535f * d) + 1.0f) : 0.0f;
    }
}

// weight transpose+cast, per layer:
//  wtm1e [128][64]  : k=0 -> mw1 row 256 (edist); k=1..50 -> rows 257..306 (rbf); else 0
//  wtp   [256][128] : n<128 -> mw1[k][n]; n>=128 -> mw1[128+k][n-128]
//  wtm2  [128][128], wtc1 [128][128], wtf [128][256]
#define SZ_M1E 8192
#define SZ_P   32768
#define SZ_M2  16384
#define SZ_C1  16384
#define SZ_F   32768
#define WT_L   (SZ_M1E + SZ_P + SZ_M2 + SZ_C1 + SZ_F)   // 106496
__global__ void wtrans_kernel(const float* __restrict__ mw1, const float* __restrict__ mw2,
                              const float* __restrict__ cw1, const float* __restrict__ fw,
                              short* __restrict__ wtm1e, short* __restrict__ wtp,
                              short* __restrict__ wtm2, short* __restrict__ wtc1,
                              short* __restrict__ wtf) {
    int idx = blockIdx.x * blockDim.x + threadIdx.x;
    if (idx >= N_LAYERS * WT_L) return;
    int l = idx / WT_L;
    int r = idx - l * WT_L;
    const float* m1 = mw1 + (size_t)l * EDGE_IN * HID;
    if (r < SZ_M1E) {
        int n = r >> 6, k = r & 63;
        float v = 0.f;
        if (k == 0) v = m1[(size_t)256 * HID + n];
        else if (k <= 50) v = m1[(size_t)(256 + k) * HID + n];
        wtm1e[(size_t)l * SZ_M1E + r] = f2bf(v);
    } else if ((r -= SZ_M1E) < SZ_P) {
        int n = r >> 7, k = r & 127;
        float v = (n < HID) ? m1[(size_t)k * HID + n]
                            : m1[(size_t)(HID + k) * HID + (n - HID)];
        wtp[(size_t)l * SZ_P + r] = f2bf(v);
    } else if ((r -= SZ_P) < SZ_M2) {
        int n = r >> 7, k = r & 127;
        wtm2[(size_t)l * SZ_M2 + r] = f2bf(mw2[(size_t)l * HID * HID + (size_t)k * HID + n]);
    } else if ((r -= SZ_M2) < SZ_C1) {
        int n = r >> 7, k = r & 127;
        wtc1[(size_t)l * SZ_C1 + r] = f2bf(cw1[(size_t)l * HID * HID + (size_t)k * HID + n]);
    } else {
        r -= SZ_C1;
        int n = r >> 8, k = r & 255;
        wtf[(size_t)l * SZ_F + r] = f2bf(fw[(size_t)l * 2 * HID * HID + (size_t)k * HID + n]);
    }
}

// ---------------- P = feats @ mw1[0:256] (layer-0 only), 32 rows/block ----------
__global__ __launch_bounds__(256) void p_kernel(
    const short* __restrict__ featsB, const short* __restrict__ wtp,
    short* __restrict__ Pg)
{
    __shared__ short sA[32][136];
    const int tid = threadIdx.x;
    const int n0 = blockIdx.x * 32;
    const int wave = tid >> 6, lane = tid & 63, quad = lane >> 4, lm = lane & 15;

    {
        int el = tid >> 3, kq = (tid & 7) * 16;
        int node = n0 + el;
        if (node < N_NODES) {
            const bf16x8* src = (const bf16x8*)&featsB[(size_t)node * HID + kq];
            *(bf16x8*)&sA[el][kq]     = src[0];
            *(bf16x8*)&sA[el][kq + 8] = src[1];
        } else {
            *(bf16x8*)&sA[el][kq]     = (bf16x8)0;
            *(bf16x8*)&sA[el][kq + 8] = (bf16x8)0;
        }
    }
    bf16x8 bw[4][4];
    #pragma unroll
    for (int h = 0; h < 4; ++h)
        #pragma unroll
        for (int nb = 0; nb < 4; ++nb) {
            int col = wave * 64 + nb * 16 + lm;
            bw[h][nb] = *(const bf16x8*)&wtp[(size_t)col * HID + h * 32 + quad * 8];
        }
    __syncthreads();

    f32x4 acc[2][4];
    #pragma unroll
    for (int mt = 0; mt < 2; ++mt)
        #pragma unroll
        for (int nb = 0; nb < 4; ++nb) acc[mt][nb] = (f32x4)0.f;

    #pragma unroll
    for (int h = 0; h < 4; ++h) {
        bf16x8 af[2];
        af[0] = *(bf16x8*)&sA[lm][h * 32 + quad * 8];
        af[1] = *(bf16x8*)&sA[16 + lm][h * 32 + quad * 8];
        #pragma unroll
        for (int nb = 0; nb < 4; ++nb) {
            acc[0][nb] = __builtin_amdgcn_mfma_f32_16x16x32_bf16(af[0], bw[h][nb], acc[0][nb], 0, 0, 0);
            acc[1][nb] = __builtin_amdgcn_mfma_f32_16x16x32_bf16(af[1], bw[h][nb], acc[1][nb], 0, 0, 0);
        }
    }
    #pragma unroll
    for (int mt = 0; mt < 2; ++mt)
        #pragma unroll
        for (int r = 0; r < 4; ++r) {
            int node = n0 + mt * 16 + quad * 4 + r;
            if (node < N_NODES) {
                #pragma unroll
                for (int nb = 0; nb < 4; ++nb) {
                    int col = wave * 64 + nb * 16 + lm;
                    Pg[(size_t)node * 256 + col] = f2bf(acc[mt][nb][r]);
                }
            }
        }
}

// ---------------- fused per-layer edge kernel (R12 structure) ----------------
// h1 = silu(P1[row]+P2[col]+[edist|rbf]@wtm1e+b1); m = silu(h1@mw2+b2);
// c1 = silu(m@cw1+cb1); w = c1.cw2+cb2; agg += m (run-reduced); coords += w*diff.

__global__ __launch_bounds__(256) void edge_kernel(
    const int* __restrict__ sorted,
    const int* __restrict__ erow, const int* __restrict__ ecol,
    const float* __restrict__ coords, float* __restrict__ coords_next,
    const short* __restrict__ Pg,
    const float* __restrict__ d0g, const float* __restrict__ cut0g,
    const short* __restrict__ wtm1e, const float* __restrict__ mb1,
    const short* __restrict__ wtm2, const float* __restrict__ mb2,
    const short* __restrict__ wtc1, const float* __restrict__ cb1,
    const float* __restrict__ cw2, const float* __restrict__ cb2,
    float* __restrict__ agg)
{
    __shared__ short sH[M_TILE][136];   // P12 -> h1 -> m
    __shared__ short sA[M_TILE][72];    // rbf K-chunk
    __shared__ int   srow[M_TILE];
    __shared__ float sdiff[M_TILE][3];
    __shared__ float sW[M_TILE];
    __shared__ float sWp[M_TILE][4];

    const int tid = threadIdx.x;
    const int p0 = blockIdx.x * M_TILE;
    const int wave = tid >> 6, lane = tid & 63, quad = lane >> 4, lm = lane & 15;
    const int colA = wave * 32 + lm, colB = colA + 16;
    const int el = tid >> 2, sub = tid & 3;

    int e = sorted[p0 + el];
    int r = erow[e], c = ecol[e];
    float dx = coords[3*r]   - coords[3*c];
    float dy = coords[3*r+1] - coords[3*c+1];
    float dz = coords[3*r+2] - coords[3*c+2];
    float ds2 = dx*dx + dy*dy + dz*dz;
    if (sub == 0) {
        srow[el] = r;
        sdiff[el][0] = dx; sdiff[el][1] = dy; sdiff[el][2] = dz;
    }
    float b1A = mb1[colA], b1B = mb1[colB];
    float b2A = mb2[colA], b2B = mb2[colB];
    float c1A = cb1[colA], c1B = cb1[colB];
    float vA  = cw2[colA], vB  = cw2[colB];
    const float cb2v = cb2[0];

    // ---- stage P12 = P1[row] + P2[col] into sH (4 thr/row, 32 cols each) ----
    {
        int kq = sub * 32;
        const short* p1 = &Pg[(size_t)r * 256 + kq];
        const short* p2 = &Pg[(size_t)c * 256 + 128 + kq];
        #pragma unroll
        for (int g = 0; g < 4; ++g) {
            bf16x8 a = *(const bf16x8*)&p1[g * 8];
            bf16x8 b = *(const bf16x8*)&p2[g * 8];
            bf16x8 o;
            #pragma unroll
            for (int j = 0; j < 8; j += 2) {
                float s0 = bf2f((unsigned short)a[j])     + bf2f((unsigned short)b[j]);
                float s1 = bf2f((unsigned short)a[j + 1]) + bf2f((unsigned short)b[j + 1]);
                unsigned u = pk_bf(s0, s1);
                o[j] = (short)(u & 0xFFFF); o[j + 1] = (short)(u >> 16);
            }
            *(bf16x8*)&sH[el][kq + g * 8] = o;
        }
    }
    // ---- stage rbf chunk into sA (4 thr/row, 16 k each): k=0 edist, 1..50 rbf ----
    {
        float dv = d0g[p0 + el], ct = cut0g[p0 + el];
        int kq = sub * 16;
        #pragma unroll
        for (int g = 0; g < 2; ++g) {
            bf16x8 v;
            #pragma unroll
            for (int j = 0; j < 8; ++j) {
                int k = kq + g * 8 + j;
                float val = 0.f;
                if (k == 0) val = ds2;
                else if (k <= N_RBF) {
                    float cen = (float)(k - 1) * (10.0f / 49.0f);
                    float t = dv - cen;
                    val = __expf(-t * t * 5.0f) * ct;
                }
                v[j] = f2bf(val);
            }
            *(bf16x8*)&sA[el][kq + g * 8] = v;
        }
    }
    // B prefetch: phase-1 + phase-2 frags ride the same pre-barrier window
    bf16x8 bw1[2][2];
    #pragma unroll
    for (int h = 0; h < 2; ++h) {
        bw1[h][0] = *(const bf16x8*)&wtm1e[(size_t)colA * 64 + h * 32 + quad * 8];
        bw1[h][1] = *(const bf16x8*)&wtm1e[(size_t)colB * 64 + h * 32 + quad * 8];
    }
    bf16x8 bw2[4][2];
    #pragma unroll
    for (int ks = 0; ks < 4; ++ks) {
        bw2[ks][0] = *(const bf16x8*)&wtm2[(size_t)colA * HID + ks * 32 + quad * 8];
        bw2[ks][1] = *(const bf16x8*)&wtm2[(size_t)colB * HID + ks * 32 + quad * 8];
    }
    __syncthreads();

    f32x4 acc[4][2];
    #pragma unroll
    for (int mt = 0; mt < 4; ++mt) { acc[mt][0] = (f32x4)0.f; acc[mt][1] = (f32x4)0.f; }

    // ---- phase 1: rbf GEMM, K=64 (16 MFMA) ----
    #pragma unroll
    for (int h = 0; h < 2; ++h) {
        bf16x8 af[4];
        #pragma unroll
        for (int mt = 0; mt < 4; ++mt)
            af[mt] = *(bf16x8*)&sA[mt * 16 + lm][h * 32 + quad * 8];
        #pragma unroll
        for (int nb = 0; nb < 2; ++nb)
            #pragma unroll
            for (int mt = 0; mt < 4; ++mt)
                acc[mt][nb] = __builtin_amdgcn_mfma_f32_16x16x32_bf16(
                    af[mt], bw1[h][nb], acc[mt][nb], 0, 0, 0);
    }
    // epilogue 1: h1 = silu(acc + P12 + b1), in-place in sH
    #pragma unroll
    for (int mt = 0; mt < 4; ++mt) {
        #pragma unroll
        for (int r2 = 0; r2 < 4; ++r2) {
            int row = mt * 16 + quad * 4 + r2;
            float pA = bf2f((unsigned short)sH[row][colA]);
            float pB = bf2f((unsigned short)sH[row][colB]);
            float hA = silu_f(acc[mt][0][r2] + pA + b1A);
            float hB = silu_f(acc[mt][1][r2] + pB + b1B);
            unsigned u = pk_bf(hA, hB);
            sH[row][colA] = (short)(u & 0xFFFF);
            sH[row][colB] = (short)(u >> 16);
        }
        acc[mt][0] = (f32x4)0.f; acc[mt][1] = (f32x4)0.f;
    }
    __syncthreads();

    // ---- phase 2: m = silu(h1 @ mw2 + b2), K=128 (32 MFMA) ----
    #pragma unroll
    for (int ks = 0; ks < 4; ++ks) {
        bf16x8 af[4];
        #pragma unroll
        for (int mt = 0; mt < 4; ++mt)
            af[mt] = *(bf16x8*)&sH[mt * 16 + lm][ks * 32 + quad * 8];
        #pragma unroll
        for (int nb = 0; nb < 2; ++nb)
            #pragma unroll
            for (int mt = 0; mt < 4; ++mt)
                acc[mt][nb] = __builtin_amdgcn_mfma_f32_16x16x32_bf16(
                    af[mt], bw2[ks][nb], acc[mt][nb], 0, 0, 0);
    }
    bf16x8 bw3[4][2];
    #pragma unroll
    for (int ks = 0; ks < 4; ++ks) {
        bw3[ks][0] = *(const bf16x8*)&wtc1[(size_t)colA * HID + ks * 32 + quad * 8];
        bw3[ks][1] = *(const bf16x8*)&wtc1[(size_t)colB * HID + ks * 32 + quad * 8];
    }
    __syncthreads();
    // epilogue 2: silu+bias; run-reduce agg atomics; write m -> sH
    #pragma unroll
    for (int nb = 0; nb < 2; ++nb) {
        int col = wave * 32 + nb * 16 + lm;
        float b = nb ? b2B : b2A;
        #pragma unroll
        for (int mt = 0; mt < 4; ++mt) {
            float g = 0.f;
            #pragma unroll
            for (int r2 = 0; r2 < 4; ++r2) {
                int row = mt * 16 + quad * 4 + r2;
                float mv = silu_f(acc[mt][nb][r2] + b);
                sH[row][col] = f2bf(mv);
                g += mv;
                if (r2 == 3 || srow[row + 1] != srow[row]) {
                    atomicAdd(&agg[(size_t)srow[row] * HID + col], g);
                    g = 0.f;
                }
            }
            acc[mt][nb] = (f32x4)0.f;
        }
    }
    __syncthreads();

    // ---- phase 3: c1 = silu(m @ cw1 + cb1), K=128 (32 MFMA) ----
    #pragma unroll
    for (int ks = 0; ks < 4; ++ks) {
        bf16x8 af[4];
        #pragma unroll
        for (int mt = 0; mt < 4; ++mt)
            af[mt] = *(bf16x8*)&sH[mt * 16 + lm][ks * 32 + quad * 8];
        #pragma unroll
        for (int nb = 0; nb < 2; ++nb)
            #pragma unroll
            for (int mt = 0; mt < 4; ++mt)
                acc[mt][nb] = __builtin_amdgcn_mfma_f32_16x16x32_bf16(
                    af[mt], bw3[ks][nb], acc[mt][nb], 0, 0, 0);
    }
    // epilogue 3: w-dot from accumulators via quad shfl-reduce
    {
        float wp[4][4];
        #pragma unroll
        for (int mt = 0; mt < 4; ++mt)
            #pragma unroll
            for (int r2 = 0; r2 < 4; ++r2) wp[mt][r2] = 0.f;
        #pragma unroll
        for (int nb = 0; nb < 2; ++nb) {
            float b = nb ? c1B : c1A;
            float vv = nb ? vB : vA;
            #pragma unroll
            for (int mt = 0; mt < 4; ++mt)
                #pragma unroll
                for (int r2 = 0; r2 < 4; ++r2)
                    wp[mt][r2] += silu_f(acc[mt][nb][r2] + b) * vv;
        }
        #pragma unroll
        for (int mt = 0; mt < 4; ++mt)
            #pragma unroll
            for (int r2 = 0; r2 < 4; ++r2) {
                float v = wp[mt][r2];
                v += __shfl_xor(v, 1); v += __shfl_xor(v, 2);
                v += __shfl_xor(v, 4); v += __shfl_xor(v, 8);
                if (lm == 0) sWp[mt * 16 + quad * 4 + r2][wave] = v;
            }
    }
    __syncthreads();
    if (tid < M_TILE)
        sW[tid] = cb2v + sWp[tid][0] + sWp[tid][1] + sWp[tid][2] + sWp[tid][3];
    __syncthreads();
    if (tid < M_TILE) {
        bool leader = (tid == 0) || (srow[tid] != srow[tid - 1]);
        if (leader) {
            int rr = srow[tid];
            float ax = 0.f, ay = 0.f, az = 0.f;
            for (int k = tid; k < M_TILE && srow[k] == rr; ++k) {
                ax += sW[k] * sdiff[k][0];
                ay += sW[k] * sdiff[k][1];
                az += sW[k] * sdiff[k][2];
            }
            atomicAdd(&coords_next[3*rr+0], ax);
            atomicAdd(&coords_next[3*rr+1], ay);
            atomicAdd(&coords_next[3*rr+2], az);
        }
    }
}

// ---------------- node update (fused, R12 structure, 32 rows/block) ----------------
// feats' = silu([feats|agg]@fw+fb); zeroes agg; copies coords; P'=feats'@wtp_next.
__global__ __launch_bounds__(256) void node_kernel(
    const short* __restrict__ featsB, float* __restrict__ agg,
    const short* __restrict__ wtf, const float* __restrict__ fb,
    short* __restrict__ outB,
    const short* __restrict__ wtp_next, short* __restrict__ Pg,
    const float* __restrict__ csrc, float* __restrict__ cdst)
{
    __shared__ short sA[32][72];
    __shared__ short sO[32][136];

    const int tid = threadIdx.x;
    const int n0 = blockIdx.x * 32;
    const int wave = tid >> 6, lane = tid & 63, quad = lane >> 4, lm = lane & 15;

    {   // coords copy for next layer (spread over grid)
        int idx = blockIdx.x * 256 + tid;
        if (idx < 3 * N_NODES) cdst[idx] = csrc[idx];
    }
    float fbA = fb[wave * 32 + lm], fbB = fb[wave * 32 + 16 + lm];

    f32x4 acc[2][2];
    acc[0][0] = (f32x4)0.f; acc[0][1] = (f32x4)0.f;
    acc[1][0] = (f32x4)0.f; acc[1][1] = (f32x4)0.f;

    for (int c = 0; c < 4; ++c) {   // K = 256, 4 chunks of 64
        int k0 = c * 64;
        bf16x8 bw[2][2];
        #pragma unroll
        for (int h = 0; h < 2; ++h) {
            int col0 = wave * 32 + lm;
            bw[h][0] = *(const bf16x8*)&wtf[(size_t)col0 * 256 + k0 + h * 32 + quad * 8];
            bw[h][1] = *(const bf16x8*)&wtf[(size_t)(col0 + 16) * 256 + k0 + h * 32 + quad * 8];
        }
        {
            int el = tid >> 3, kq = (tid & 7) * 8;
            int node = n0 + el;
            if (node < N_NODES) {
                if (c < 2) {
                    *(bf16x8*)&sA[el][kq] =
                        *(const bf16x8*)&featsB[(size_t)node * HID + k0 + kq];
                } else {
                    float* ap = &agg[(size_t)node * HID + (k0 - 128) + kq];
                    bf16x8 v;
                    #pragma unroll
                    for (int j = 0; j < 8; j += 2) {
                        unsigned u = pk_bf(ap[j], ap[j + 1]);
                        v[j] = (short)(u & 0xFFFF); v[j + 1] = (short)(u >> 16);
                    }
                    *(bf16x8*)&sA[el][kq] = v;
                    // zero agg for the next layer (each element touched exactly once)
                    *(float4*)&ap[0] = make_float4(0.f, 0.f, 0.f, 0.f);
                    *(float4*)&ap[4] = make_float4(0.f, 0.f, 0.f, 0.f);
                }
            } else {
                *(bf16x8*)&sA[el][kq] = (bf16x8)0;
            }
        }
        __syncthreads();
        #pragma unroll
        for (int h = 0; h < 2; ++h) {
            bf16x8 af[2];
            af[0] = *(bf16x8*)&sA[lm][h * 32 + quad * 8];
            af[1] = *(bf16x8*)&sA[16 + lm][h * 32 + quad * 8];
            #pragma unroll
            for (int nb = 0; nb < 2; ++nb) {
                acc[0][nb] = __builtin_amdgcn_mfma_f32_16x16x32_bf16(af[0], bw[h][nb], acc[0][nb], 0, 0, 0);
                acc[1][nb] = __builtin_amdgcn_mfma_f32_16x16x32_bf16(af[1], bw[h][nb], acc[1][nb], 0, 0, 0);
            }
        }
        __syncthreads();
    }
    // prefetch P-GEMM B frags (latency hidden by epilogue)
    bf16x8 bwp[4][4];
    if (wtp_next) {
        #pragma unroll
        for (int ks = 0; ks < 4; ++ks)
            #pragma unroll
            for (int nb = 0; nb < 4; ++nb) {
                int col = wave * 64 + nb * 16 + lm;
                bwp[ks][nb] = *(const bf16x8*)&wtp_next[(size_t)col * HID + ks * 32 + quad * 8];
            }
    }
    // epilogue: silu+bias -> sO
    #pragma unroll
    for (int mt = 0; mt < 2; ++mt) {
        #pragma unroll
        for (int r = 0; r < 4; ++r) {
            int row = mt * 16 + quad * 4 + r;
            float hA = silu_f(acc[mt][0][r] + fbA);
            float hB = silu_f(acc[mt][1][r] + fbB);
            unsigned u = pk_bf(hA, hB);
            sO[row][wave * 32 + lm]      = (short)(u & 0xFFFF);
            sO[row][wave * 32 + 16 + lm] = (short)(u >> 16);
        }
    }
    __syncthreads();
    {   // coalesced feats' write
        int row = tid >> 3, ch = (tid & 7) * 8;
        int node = n0 + row;
        if (node < N_NODES) {
            *(bf16x8*)&outB[(size_t)node * HID + ch]      = *(bf16x8*)&sO[row][ch];
            *(bf16x8*)&outB[(size_t)node * HID + 64 + ch] = *(bf16x8*)&sO[row][64 + ch];
        }
    }
    // ---- P' = feats' @ wtp_next (K=128, 256 cols), reads sO ----
    if (wtp_next) {
        f32x4 ap2[2][4];
        #pragma unroll
        for (int mt = 0; mt < 2; ++mt)
            #pragma unroll
            for (int nb = 0; nb < 4; ++nb) ap2[mt][nb] = (f32x4)0.f;
        #pragma unroll
        for (int ks = 0; ks < 4; ++ks) {
            bf16x8 af[2];
            af[0] = *(bf16x8*)&sO[lm][ks * 32 + quad * 8];
            af[1] = *(bf16x8*)&sO[16 + lm][ks * 32 + quad * 8];
            #pragma unroll
            for (int nb = 0; nb < 4; ++nb) {
                ap2[0][nb] = __builtin_amdgcn_mfma_f32_16x16x32_bf16(af[0], bwp[ks][nb], ap2[0][nb], 0, 0, 0);
                ap2[1][nb] = __builtin_amdgcn_mfma_f32_16x16x32_bf16(af[1], bwp[ks][nb], ap2[1][nb], 0, 0, 0);
            }
        }
        #pragma unroll
        for (int mt = 0; mt < 2; ++mt)
            #pragma unroll
            for (int r = 0; r < 4; ++r) {
                int node = n0 + mt * 16 + quad * 4 + r;
                if (node < N_NODES) {
                    #pragma unroll
                    for (int nb = 0; nb < 4; ++nb) {
                        int col = wave * 64 + nb * 16 + lm;
                        Pg[(size_t)node * 256 + col] = f2bf(ap2[mt][nb][r]);
                    }
                }
            }
    }
}

// ---------------- energy head + global sum ----------------
#define FMA8(r, aq) \
    acc[r][0] += (aq)*b0.x; acc[r][1] += (aq)*b0.y; acc[r][2] += (aq)*b0.z; acc[r][3] += (aq)*b0.w; \
    acc[r][4] += (aq)*b1.x; acc[r][5] += (aq)*b1.y; acc[r][6] += (aq)*b1.z; acc[r][7] += (aq)*b1.w;

__global__ __launch_bounds__(256) void energy_kernel(
    const short* __restrict__ featsB,
    const float* __restrict__ ew1, const float* __restrict__ eb1,
    const float* __restrict__ ew2, const float* __restrict__ eb2,
    float* __restrict__ out)
{
    __shared__ float sA[64][20];
    __shared__ float sB[16][HID];
    __shared__ float sV[HID];
    __shared__ float red[256];
    int tid = threadIdx.x;
    int n0 = blockIdx.x * 64;
    const int tr = tid >> 4, tc = tid & 15;
    const int r0 = tr * 4, c0 = tc * 4, c1 = c0 + 64;
    const int el = tid >> 2, kq = (tid & 3) * 4;

    if (tid < HID) sV[tid] = ew2[tid];

    float acc[4][8];
    #pragma unroll
    for (int i = 0; i < 4; i++)
        #pragma unroll
        for (int j = 0; j < 8; j++) acc[i][j] = 0.f;

    for (int kt = 0; kt < 8; ++kt) {   // K = 128
        int k0 = kt * 16;
        {
            int k = k0 + kq;
            int node = n0 + el;
            float4 v = make_float4(0,0,0,0);
            if (node < N_NODES) {
                const unsigned short* p = (const unsigned short*)&featsB[(size_t)node * HID + k];
                v.x = bf2f(p[0]); v.y = bf2f(p[1]); v.z = bf2f(p[2]); v.w = bf2f(p[3]);
            }
            *(float4*)&sA[el][kq] = v;
        }
        {
            int bk = tid >> 4, bj = (tid & 15) * 8;
            int k = k0 + bk;
            *(float4*)&sB[bk][bj]     = *(const float4*)&ew1[(size_t)k * HID + bj];
            *(float4*)&sB[bk][bj + 4] = *(const float4*)&ew1[(size_t)k * HID + bj + 4];
        }
        __syncthreads();
        #pragma unroll
        for (int kk4 = 0; kk4 < 4; ++kk4) {
            float4 a0 = *(const float4*)&sA[r0 + 0][kk4 * 4];
            float4 a1 = *(const float4*)&sA[r0 + 1][kk4 * 4];
            float4 a2 = *(const float4*)&sA[r0 + 2][kk4 * 4];
            float4 a3 = *(const float4*)&sA[r0 + 3][kk4 * 4];
            #pragma unroll
            for (int q = 0; q < 4; ++q) {
                int kk = kk4 * 4 + q;
                float4 b0 = *(const float4*)&sB[kk][c0];
                float4 b1 = *(const float4*)&sB[kk][c1];
                float q0 = ((const float*)&a0)[q], q1 = ((const float*)&a1)[q];
                float q2 = ((const float*)&a2)[q], q3 = ((const float*)&a3)[q];
                FMA8(0, q0) FMA8(1, q1) FMA8(2, q2) FMA8(3, q3)
            }
        }
        __syncthreads();
    }
    float part = 0.f;
    #pragma unroll
    for (int i = 0; i < 4; i++) {
        int node = n0 + r0 + i;
        if (node < N_NODES) {
            #pragma unroll
            for (int j = 0; j < 4; j++) {
                part += silu_f(acc[i][j]     + eb1[c0+j]) * sV[c0+j];
                part += silu_f(acc[i][4 + j] + eb1[c1+j]) * sV[c1+j];
            }
        }
    }
    red[tid] = part;
    __syncthreads();
    for (int s = 128; s > 0; s >>= 1) {
        if (tid < s) red[tid] += red[tid + s];
        __syncthreads();
    }
    if (tid == 0) {
        float v = red[0];
        if (blockIdx.x == 0) v += eb2[0] * (float)N_NODES;
        atomicAdd(out, v);
    }
}

// ---------------- launcher ----------------

extern "C" void kernel_launch(void* const* d_in, const int* in_sizes, int n_in,
                              void* d_out, int out_size, void* d_ws, size_t ws_size,
                              hipStream_t stream)
{
    const int*   an     = (const int*)  d_in[0];
    const float* coords = (const float*)d_in[1];
    const int*   ei     = (const int*)  d_in[2];
    const float* embed  = (const float*)d_in[3];
    const float* mw1 = (const float*)d_in[4];
    const float* mb1 = (const float*)d_in[5];
    const float* mw2 = (const float*)d_in[6];
    const float* mb2 = (const float*)d_in[7];
    const float* cw1 = (const float*)d_in[8];
    const float* cb1 = (const float*)d_in[9];
    const float* cw2 = (const float*)d_in[10];
    const float* cb2 = (const float*)d_in[11];
    const float* fw  = (const float*)d_in[12];
    const float* fb  = (const float*)d_in[13];
    const float* ew1 = (const float*)d_in[14];
    const float* eb1 = (const float*)d_in[15];
    const float* ew2 = (const float*)d_in[16];
    const float* eb2 = (const float*)d_in[17];
    float* out = (float*)d_out;

    char* w = (char*)d_ws;
    size_t off = 0;
    auto alloc = [&](size_t bytes) -> char* {
        char* p = w + off;
        off = (off + bytes + 511) & ~(size_t)511;
        return p;
    };
    short* featsB0 = (short*)alloc((size_t)N_NODES * HID * 2);
    short* featsB1 = (short*)alloc((size_t)N_NODES * HID * 2);
    short* Pg      = (short*)alloc((size_t)N_NODES * 256 * 2);
    float* agg     = (float*)alloc((size_t)N_NODES * HID * 4);
    float* cA      = (float*)alloc((size_t)N_NODES * 3 * 4);
    float* cB      = (float*)alloc((size_t)N_NODES * 3 * 4);
    float* d0      = (float*)alloc((size_t)N_EDGES * 4);
    float* cut0    = (float*)alloc((size_t)N_EDGES * 4);
    int*   sorted  = (int*)  alloc((size_t)N_EDGES * 4);
    int*   cnt     = (int*)  alloc((size_t)N_NODES * 4);
    int*   cursor  = (int*)  alloc((size_t)N_NODES * 4);
    int*   bsum    = (int*)  alloc((size_t)64 * 4);
    short* wtm1e   = (short*)alloc((size_t)N_LAYERS * SZ_M1E * 2);
    short* wtp     = (short*)alloc((size_t)N_LAYERS * SZ_P * 2);
    short* wtm2    = (short*)alloc((size_t)N_LAYERS * SZ_M2 * 2);
    short* wtc1    = (short*)alloc((size_t)N_LAYERS * SZ_C1 * 2);
    short* wtf     = (short*)alloc((size_t)N_LAYERS * SZ_F * 2);

    const int* erow = ei;
    const int* ecol = ei + N_EDGES;

    hipMemsetAsync(cnt, 0, (size_t)N_NODES * 4, stream);
    hipMemsetAsync(agg, 0, (size_t)N_NODES * HID * 4, stream);
    init_feats_kernel<<<(N_NODES * HID + 255) / 256, 256, 0, stream>>>(an, embed, featsB0);
    wtrans_kernel<<<(N_LAYERS * WT_L + 255) / 256, 256, 0, stream>>>(
        mw1, mw2, cw1, fw, wtm1e, wtp, wtm2, wtc1, wtf);
    hipMemcpyAsync(cA, coords, (size_t)N_NODES * 3 * 4, hipMemcpyDeviceToDevice, stream);
    hipMemcpyAsync(cB, coords, (size_t)N_NODES * 3 * 4, hipMemcpyDeviceToDevice, stream);
    hist_kernel<<<(N_EDGES + 255) / 256, 256, 0, stream>>>(erow, cnt);
    scan_block_kernel<<<SCAN_NB, 256, 0, stream>>>(cnt, cursor, bsum);
    scan_tops_kernel<<<1, 64, 0, stream>>>(bsum);
    scatter_kernel<<<(N_EDGES + 255) / 256, 256, 0, stream>>>(erow, cursor, bsum, sorted);
    edgegeom_kernel<<<N_EDGES / 256, 256, 0, stream>>>(sorted, erow, ecol, cA, d0, cut0);
    p_kernel<<<(N_NODES + 31) / 32, 256, 0, stream>>>(featsB0, wtp, Pg);

    short* fc = featsB0; short* fn = featsB1;
    float* cc = cA;      float* cn = cB;
    for (int l = 0; l < N_LAYERS; ++l) {
        edge_kernel<<<N_TILES, 256, 0, stream>>>(
            sorted, erow, ecol, cc, cn, Pg, d0, cut0,
            wtm1e + (size_t)l * SZ_M1E, mb1 + (size_t)l * HID,
            wtm2  + (size_t)l * SZ_M2,  mb2 + (size_t)l * HID,
            wtc1  + (size_t)l * SZ_C1,  cb1 + (size_t)l * HID,
            cw2 + (size_t)l * HID,      cb2 + l, agg);
        node_kernel<<<(N_NODES + 31) / 32, 256, 0, stream>>>(
            fc, agg, wtf + (size_t)l * SZ_F, fb + (size_t)l * HID, fn,
            (l + 1 < N_LAYERS) ? (wtp + (size_t)(l + 1) * SZ_P) : (const short*)nullptr,
            Pg, cn, cc);
        { short* t = fc; fc = fn; fn = t; }
        { float* t = cc; cc = cn; cn = t; }
    }
    hipMemsetAsync(out, 0, 4, stream);
    energy_kernel<<<(N_NODES + 63) / 64, 256, 0, stream>>>(fc, ew1, eb1, ew2, eb2, out);
}